// Round 6
// baseline (461.020 us; speedup 1.0000x reference)
//
#include <hip/hip_runtime.h>
#include <hip/hip_bf16.h>

typedef unsigned short u16;
typedef unsigned int   u32;
typedef short  s16x8  __attribute__((ext_vector_type(8)));
typedef float  f32x16 __attribute__((ext_vector_type(16)));

#define HEADS 16
#define D     192
#define NUP   1024

// ---- workspace layout (bytes) ----
#define XB       (2048ull*192*2)               // 786432
#define XH_OFF   0ull
#define XL_OFF   (XH_OFF + XB)
#define XT_OFF   (XL_OFF + XB)
#define WM_BYTES (64ull*192*192*2)             // 4718592
#define WTP_OFF  (XT_OFF + XB)
#define MTH_OFF  (WTP_OFF + WM_BYTES)
#define MTL_OFF  (MTH_OFF + WM_BYTES)
#define QF_BYTES (64ull*32*12*64*8*2)          // 25165824 (bf16 frags)
#define QFH_OFF  (MTL_OFF + WM_BYTES)
#define QFL_OFF  (QFH_OFF + QF_BYTES)
#define Y_BYTES  (64ull*1024*192*2)            // 25165824 (bf16)
#define Y_OFF    (QFL_OFF + QF_BYTES)
#define WS_NEED  (Y_OFF + Y_BYTES)             // 92012544

__device__ __forceinline__ u16 f2bf(float v) {
    __hip_bfloat16 b = __float2bfloat16(v);
    return __builtin_bit_cast(u16, b);
}
__device__ __forceinline__ u32 pk2bf(float a, float b) {
    return (u32)f2bf(a) | ((u32)f2bf(b) << 16);
}

// =====================================================================
// Prep A: x -> xh,xl (row-major [2048][192]) and xT ([64 tiles][192][32], hi)
// =====================================================================
__global__ __launch_bounds__(512)
void prep_x(const float* __restrict__ x, u16* __restrict__ xh,
            u16* __restrict__ xl, u16* __restrict__ xT)
{
    int i = blockIdx.x*512 + threadIdx.x;      // < 2048*192
    float v = x[i];
    int n = i / D, d = i - n*D;
    u16 hi = f2bf(v);
    float hf = __bfloat162float(__builtin_bit_cast(__hip_bfloat16, hi));
    xh[i] = hi;
    xl[i] = f2bf(v - hf);
    xT[(size_t)(n >> 5)*6144 + d*32 + (n & 31)] = hi;
}

// =====================================================================
// Prep B: build frag-permuted WT (from A, hi only) and MT hi/lo (from M).
// Logical: T[th][dout=(g,z,bit0)][din=(f,z2,bit1)], z2==z else 0:
//   bit0==0: bit1==0 -> +S0, bit1==1 -> -S1
//   bit0==1: bit1==0 -> +S1, bit1==1 -> +S0
// where S = A[h][g][f][z][:] for WT, S = M[h][f][g][z][:] for MT.
// Stored permuted: [((th*6+ob)*12+ks)*64 + g32*32 + l31]*8 + j
// =====================================================================
__global__ __launch_bounds__(512)
void prep_wm(const float* __restrict__ Muu, const float* __restrict__ Mdd,
             const float* __restrict__ Mud, const float* __restrict__ Mdu,
             const float* __restrict__ Auu, const float* __restrict__ Add,
             const float* __restrict__ Aud, const float* __restrict__ Adu,
             u16* __restrict__ wtp, u16* __restrict__ mth, u16* __restrict__ mtl)
{
    int idx = blockIdx.x*512 + threadIdx.x;    // < 64*36864
    int th = idx / 36864, r = idx - th*36864;
    int dout = r / 192, din = r - dout*192;
    int t = th >> 4, h = th & 15;
    const float* Ap = (t==0)?Auu:(t==1)?Aud:(t==2)?Add:Adu;
    const float* Mp = (t==0)?Muu:(t==1)?Mud:(t==2)?Mdd:Mdu;
    int g = dout / 6, zc = dout - g*6, z = zc >> 1, b0 = zc & 1;
    int f = din / 6,  zb = din - f*6,  z2 = zb >> 1, b1 = zb & 1;

    float wv = 0.0f, mv = 0.0f;
    if (z2 == z) {
        const float* a = Ap + (((size_t)h*32 + g)*32 + f)*6 + z*2;
        float A0 = a[0], A1 = a[1];
        wv = (b0 == 0) ? (b1 == 0 ? A0 : -A1) : (b1 == 0 ? A1 : A0);
        const float* m = Mp + (((size_t)h*32 + f)*32 + g)*6 + z*2;
        float M0 = m[0], M1 = m[1];
        mv = (b0 == 0) ? (b1 == 0 ? M0 : -M1) : (b1 == 0 ? M1 : M0);
    }
    int ob = dout >> 5, l31 = dout & 31;
    int ks = din >> 4, kr = din & 15, g32 = kr >> 3, j = kr & 7;
    size_t pidx = ((((size_t)th*6 + ob)*12 + ks)*64 + g32*32 + l31)*8 + j;
    wtp[pidx] = f2bf(wv);
    u16 mh = f2bf(mv);
    float mhf = __bfloat162float(__builtin_bit_cast(__hip_bfloat16, mh));
    mth[pidx] = mh;
    mtl[pidx] = f2bf(mv - mhf);
}

// =====================================================================
// helper: assemble B-fragment (32x32x16, K=16) from 4 packed-pair u32s
// held in D-frag order (m = (r&3)+8*(r>>2)+4*(lane>>5)) via half-swap
// =====================================================================
__device__ __forceinline__ s16x8 make_bfrag(u32 q0, u32 q1, u32 q2, u32 q3, bool hi) {
    u32 s0 = (u32)__shfl_xor((int)q0, 32);
    u32 s1 = (u32)__shfl_xor((int)q1, 32);
    u32 s2 = (u32)__shfl_xor((int)q2, 32);
    u32 s3 = (u32)__shfl_xor((int)q3, 32);
    uint4 w;
    w.x = hi ? s2 : q0;  w.y = hi ? s3 : q1;
    w.z = hi ? q2 : s0;  w.w = hi ? q3 : s1;
    return __builtin_bit_cast(s16x8, w);
}

// =====================================================================
// Prep C: QM score-B-fragments via MFMA (register-light, no spill).
// Per wave: one 32-row q-tile of one (t,h); 216 MFMA; stores assembled
// hi/lo fragments: qfh/qfl[((th*32+ntile)*12 + ks)*64 + lane][8 u16]
// =====================================================================
__global__ __launch_bounds__(256, 2)
void prep_qmf(const u16* __restrict__ xh_g, const u16* __restrict__ xl_g,
              const u16* __restrict__ mth_g, const u16* __restrict__ mtl_g,
              u16* __restrict__ qfh, u16* __restrict__ qfl)
{
    const int nt = blockIdx.x, h = blockIdx.y, t = blockIdx.z;
    const int tid  = threadIdx.x;
    const int lane = tid & 63;
    const int l31  = lane & 31;
    const int g32  = lane >> 5;
    const int wave = tid >> 6;
    const int th   = t*16 + h;
    const int ntile = nt*4 + wave;
    const int n0   = ntile*32;
    const int qoff = (t <= 1) ? 0 : NUP;

    s16x8 bxh[12], bxl[12];
    const u16* xrh = xh_g + (size_t)(qoff + n0 + l31)*D;
    const u16* xrl = xl_g + (size_t)(qoff + n0 + l31)*D;
    #pragma unroll
    for (int ks = 0; ks < 12; ++ks) {
        bxh[ks] = *reinterpret_cast<const s16x8*>(xrh + ks*16 + g32*8);
        bxl[ks] = *reinterpret_cast<const s16x8*>(xrl + ks*16 + g32*8);
    }
    const u16* mthb = mth_g + (size_t)th*36864;
    const u16* mtlb = mtl_g + (size_t)th*36864;
    u16* qhb = qfh + (((size_t)th*32 + ntile)*12)*64*8;
    u16* qlb = qfl + (((size_t)th*32 + ntile)*12)*64*8;

    #pragma unroll
    for (int ob = 0; ob < 6; ++ob) {
        f32x16 a;
        #pragma unroll
        for (int i = 0; i < 16; ++i) a[i] = 0.0f;
        #pragma unroll
        for (int ks = 0; ks < 12; ++ks) {
            size_t fo = (((size_t)ob*12 + ks)*64 + lane)*8;
            s16x8 amh = *reinterpret_cast<const s16x8*>(mthb + fo);
            s16x8 aml = *reinterpret_cast<const s16x8*>(mtlb + fo);
            a = __builtin_amdgcn_mfma_f32_32x32x16_bf16(amh, bxh[ks], a, 0, 0, 0);
            a = __builtin_amdgcn_mfma_f32_32x32x16_bf16(amh, bxl[ks], a, 0, 0, 0);
            a = __builtin_amdgcn_mfma_f32_32x32x16_bf16(aml, bxh[ks], a, 0, 0, 0);
        }
        u32 hq[8], lq[8];
        #pragma unroll
        for (int j = 0; j < 8; ++j) {
            float v0 = a[2*j], v1 = a[2*j+1];
            u32 hw = pk2bf(v0, v1);
            float h0 = __builtin_bit_cast(float, hw << 16);
            float h1 = __builtin_bit_cast(float, hw & 0xffff0000u);
            hq[j] = hw;
            lq[j] = pk2bf(v0 - h0, v1 - h1);
        }
        s16x8 fh0 = make_bfrag(hq[0], hq[1], hq[2], hq[3], g32);
        s16x8 fh1 = make_bfrag(hq[4], hq[5], hq[6], hq[7], g32);
        s16x8 fl0 = make_bfrag(lq[0], lq[1], lq[2], lq[3], g32);
        s16x8 fl1 = make_bfrag(lq[4], lq[5], lq[6], lq[7], g32);
        *reinterpret_cast<uint4*>(qhb + ((size_t)(ob*2+0)*64 + lane)*8) = __builtin_bit_cast(uint4, fh0);
        *reinterpret_cast<uint4*>(qhb + ((size_t)(ob*2+1)*64 + lane)*8) = __builtin_bit_cast(uint4, fh1);
        *reinterpret_cast<uint4*>(qlb + ((size_t)(ob*2+0)*64 + lane)*8) = __builtin_bit_cast(uint4, fl0);
        *reinterpret_cast<uint4*>(qlb + ((size_t)(ob*2+1)*64 + lane)*8) = __builtin_bit_cast(uint4, fl1);
    }
}

// =====================================================================
// Main fused kernel: 4 waves x 32 q-rows = 128 q-rows per block.
// BOTH QM fragment sets streamed from L2 each iteration (anti-LICM via
// opaque asm on the per-lane offset) -> VGPR live ~110, no spill.
// Loads for tile t+1 issued right after staging so the next barrier's
// drain is hidden under compute.
// =====================================================================
__global__ __launch_bounds__(256, 2)
void attn_mfma(const u16* __restrict__ xh_g,  const u16* __restrict__ xl_g,
               const u16* __restrict__ xT_g,  const u16* __restrict__ wtp_g,
               const u16* __restrict__ qfh_g, const u16* __restrict__ qfl_g,
               u16* __restrict__ y_g)
{
    const int nt = blockIdx.x, h = blockIdx.y, t = blockIdx.z;
    const int tid  = threadIdx.x;
    const int lane = tid & 63;
    const int l31  = lane & 31;
    const int g32  = lane >> 5;
    const int wave = tid >> 6;
    const int th   = t*16 + h;
    const int n0   = nt*128 + wave*32;
    const int koff = (t == 1 || t == 2) ? NUP : 0;   // k/v-side rows
    const int mtb  = koff >> 5;

    __shared__ u16 sXh[32*200];
    __shared__ u16 sXl[32*200];
    __shared__ u16 sXT[192*40];

    // per-lane byte offset into the fragment arrays (same for hi and lo)
    const u32 qf_off0 = (u32)(((((u32)th*32 + (u32)(n0 >> 5))*12)*64 + (u32)lane)*16);

    f32x16 vt[6];
    #pragma unroll
    for (int ob = 0; ob < 6; ++ob)
        #pragma unroll
        for (int i = 0; i < 16; ++i) vt[ob][i] = 0.0f;

    float run_m = -3.0e38f, run_l = 0.0f;

    uint4 ld[9];
    auto load_tile = [&](int mt) {
        const int krow0 = koff + mt*32;
        #pragma unroll
        for (int i = 0; i < 9; ++i) {
            int c = tid + i*256;
            const u16* gp;
            if (c < 768) {
                int rr = c/24, cc = c - rr*24;
                gp = xh_g + (size_t)(krow0 + rr)*D + cc*8;
            } else if (c < 1536) {
                int c2 = c - 768, rr = c2/24, cc = c2 - rr*24;
                gp = xl_g + (size_t)(krow0 + rr)*D + cc*8;
            } else {
                int c3 = c - 1536, dd = c3 >> 2, qq = c3 & 3;
                gp = xT_g + (size_t)(mtb + mt)*6144 + dd*32 + qq*8;
            }
            ld[i] = *reinterpret_cast<const uint4*>(gp);
        }
    };

    load_tile(0);

    for (int mt = 0; mt < 32; ++mt) {
        __syncthreads();   // A: prev compute done with LDS; ld(mt) arrived
        // write LDS (padded strides)
        #pragma unroll
        for (int i = 0; i < 9; ++i) {
            int c = tid + i*256;
            u16* lp;
            if (c < 768) {
                int rr = c/24, cc = c - rr*24;  lp = sXh + rr*200 + cc*8;
            } else if (c < 1536) {
                int c2 = c - 768, rr = c2/24, cc = c2 - rr*24; lp = sXl + rr*200 + cc*8;
            } else {
                int c3 = c - 1536, dd = c3 >> 2, qq = c3 & 3;  lp = sXT + dd*40 + qq*8;
            }
            *reinterpret_cast<uint4*>(lp) = ld[i];
        }
        __syncthreads();   // B: staged
        if (mt < 31) load_tile(mt+1);     // issue now; hidden under compute

        // C) scores: St[m32][n32] = Xk * QM^T, 3-term split.
        // Both fragment sets streamed from L2; opaque offset defeats LICM
        // so they never become loop-carried register residents.
        u32 qoffv = qf_off0;
        asm volatile("" : "+v"(qoffv));
        const char* qhp = (const char*)qfh_g + qoffv;
        const char* qlp = (const char*)qfl_g + qoffv;

        f32x16 s;
        #pragma unroll
        for (int i = 0; i < 16; ++i) s[i] = 0.0f;
        __builtin_amdgcn_s_setprio(1);
        #pragma unroll
        for (int ks = 0; ks < 12; ++ks) {
            s16x8 qhk = *reinterpret_cast<const s16x8*>(qhp + ks*1024);
            s16x8 qlk = *reinterpret_cast<const s16x8*>(qlp + ks*1024);
            s16x8 ah = *reinterpret_cast<const s16x8*>(sXh + l31*200 + ks*16 + g32*8);
            s16x8 al = *reinterpret_cast<const s16x8*>(sXl + l31*200 + ks*16 + g32*8);
            s = __builtin_amdgcn_mfma_f32_32x32x16_bf16(ah, qhk, s, 0, 0, 0);
            s = __builtin_amdgcn_mfma_f32_32x32x16_bf16(ah, qlk, s, 0, 0, 0);
            s = __builtin_amdgcn_mfma_f32_32x32x16_bf16(al, qhk, s, 0, 0, 0);
        }
        __builtin_amdgcn_s_setprio(0);

        // D) online softmax (col n = l31; lane holds 16 of 32 m values)
        float tmax = s[0];
        #pragma unroll
        for (int i = 1; i < 16; ++i) tmax = fmaxf(tmax, s[i]);
        tmax = fmaxf(tmax, __shfl_xor(tmax, 32));
        if (__any(tmax > run_m + 8.0f)) {       // defer-rescale (T13)
            float nm = fmaxf(run_m, tmax);
            float rs = __expf(run_m - nm);
            #pragma unroll
            for (int ob = 0; ob < 6; ++ob)
                #pragma unroll
                for (int i = 0; i < 16; ++i) vt[ob][i] *= rs;
            run_l *= rs;
            run_m = nm;
        }
        float p[16];
        float psum = 0.0f;
        #pragma unroll
        for (int i = 0; i < 16; ++i) { p[i] = __expf(s[i] - run_m); psum += p[i]; }
        psum += __shfl_xor(psum, 32);
        run_l += psum;

        // E) P -> bf16 B-fragments (in-register, half-swap)
        u32 q[8];
        #pragma unroll
        for (int j = 0; j < 8; ++j) q[j] = pk2bf(p[2*j], p[2*j+1]);
        s16x8 pf0 = make_bfrag(q[0], q[1], q[2], q[3], g32);
        s16x8 pf1 = make_bfrag(q[4], q[5], q[6], q[7], g32);

        // F) PV: Vt^T[d][n] += X^T * P
        __builtin_amdgcn_s_setprio(1);
        #pragma unroll
        for (int ob = 0; ob < 6; ++ob) {
            s16x8 a0 = *reinterpret_cast<const s16x8*>(sXT + (ob*32 + l31)*40 + g32*8);
            s16x8 a1 = *reinterpret_cast<const s16x8*>(sXT + (ob*32 + l31)*40 + 16 + g32*8);
            vt[ob] = __builtin_amdgcn_mfma_f32_32x32x16_bf16(a0, pf0, vt[ob], 0, 0, 0);
            vt[ob] = __builtin_amdgcn_mfma_f32_32x32x16_bf16(a1, pf1, vt[ob], 0, 0, 0);
        }
        __builtin_amdgcn_s_setprio(0);
    }

    // --- normalize ---
    float inv = 1.0f / run_l;
    #pragma unroll
    for (int ob = 0; ob < 6; ++ob)
        #pragma unroll
        for (int i = 0; i < 16; ++i) vt[ob][i] *= inv;

    // --- combine: Y^T[dout][n] = sum_din WT[dout][din] * Vt^T[din][n] ---
    const u16* wbase = wtp_g + (size_t)th*36864;
    f32x16 y[6];
    #pragma unroll
    for (int ob = 0; ob < 6; ++ob)
        #pragma unroll
        for (int i = 0; i < 16; ++i) y[ob][i] = 0.0f;

    #pragma unroll
    for (int ob = 0; ob < 6; ++ob) {
        u32 qq[8];
        #pragma unroll
        for (int j = 0; j < 8; ++j) qq[j] = pk2bf(vt[ob][2*j], vt[ob][2*j+1]);
        #pragma unroll
        for (int half = 0; half < 2; ++half) {
            int ks = ob*2 + half;
            s16x8 b = half ? make_bfrag(qq[4], qq[5], qq[6], qq[7], g32)
                           : make_bfrag(qq[0], qq[1], qq[2], qq[3], g32);
            #pragma unroll
            for (int ob2 = 0; ob2 < 6; ++ob2) {
                s16x8 a = *reinterpret_cast<const s16x8*>(
                    wbase + ((((size_t)ob2*12) + ks)*64 + lane)*8);
                y[ob2] = __builtin_amdgcn_mfma_f32_32x32x16_bf16(a, b, y[ob2], 0, 0, 0);
            }
        }
    }

    // --- write partial Y[t][h][n][dout] (bf16) ---
    u16* yrow = y_g + ((size_t)th*1024 + n0 + l31)*D;
    #pragma unroll
    for (int ob = 0; ob < 6; ++ob)
        #pragma unroll
        for (int rq = 0; rq < 4; ++rq) {
            uint2 v;
            v.x = pk2bf(y[ob][rq*4+0], y[ob][rq*4+1]);
            v.y = pk2bf(y[ob][rq*4+2], y[ob][rq*4+3]);
            *reinterpret_cast<uint2*>(yrow + ob*32 + rq*8 + g32*4) = v;
        }
}

// =====================================================================
// Reduce: out[p*1024+n][d] = sum_{t in pair, h} y[t][h][n][d]  (bf16 in)
// =====================================================================
__global__ __launch_bounds__(512)
void reduce_y(const u16* __restrict__ y_g, float* __restrict__ out)
{
    int gi = blockIdx.x*512 + threadIdx.x;     // < 2048*192/8
    int n = gi / 24, c = gi - n*24;
    int p = n >> 10, nn = n & 1023;
    float acc[8];
    #pragma unroll
    for (int j = 0; j < 8; ++j) acc[j] = 0.0f;
    #pragma unroll
    for (int k = 0; k < 32; ++k) {
        int tcur = p*2 + (k >> 4), hh = k & 15;
        uint4 v = *reinterpret_cast<const uint4*>(
            y_g + ((size_t)((tcur*16+hh)*1024 + nn))*D + c*8);
        u32 w[4] = {v.x, v.y, v.z, v.w};
        #pragma unroll
        for (int j = 0; j < 4; ++j) {
            acc[2*j]   += __builtin_bit_cast(float, w[j] << 16);
            acc[2*j+1] += __builtin_bit_cast(float, w[j] & 0xffff0000u);
        }
    }
    float* op = out + (size_t)n*D + c*8;
    float4 o0 = {acc[0], acc[1], acc[2], acc[3]};
    float4 o1 = {acc[4], acc[5], acc[6], acc[7]};
    *reinterpret_cast<float4*>(op)     = o0;
    *reinterpret_cast<float4*>(op + 4) = o1;
}

// =====================================================================
// Fallback (round-1 fp32 kernel) if ws too small
// =====================================================================
__global__ __launch_bounds__(256, 2)
void attn_fused_fb(const float* __restrict__ x,
                const float* __restrict__ Muu, const float* __restrict__ Mdd,
                const float* __restrict__ Mud, const float* __restrict__ Mdu,
                const float* __restrict__ Auu, const float* __restrict__ Add,
                const float* __restrict__ Aud, const float* __restrict__ Adu,
                float* __restrict__ out)
{
    const int nt  = blockIdx.x;
    const int h   = blockIdx.y;
    const int t   = blockIdx.z;
    const int tid = threadIdx.x;
    const float* qb = (t <= 1) ? x : x + (size_t)NUP*D;
    const float* kb = (t == 0 || t == 3) ? x : x + (size_t)NUP*D;
    const float* Mp = (t==0)?Muu:(t==1)?Mud:(t==2)?Mdd:Mdu;
    const float* Ap = (t==0)?Auu:(t==1)?Aud:(t==2)?Add:Adu;
    const float* Mh = Mp + (size_t)h*32*D;
    const float* Ah = Ap + (size_t)h*32*D;
    float* ob = out + ((t>=2) ? (size_t)NUP*D : 0);

    __shared__ float sK[32*196];
    __shared__ float sQM[32*196];
    __shared__ float sS[32*33];
    __shared__ float sTmp[32*8];
    __shared__ float sR[32];
    __shared__ float sMaxRun[32];
    __shared__ float sSumRun[32];

    if (tid < 32) { sMaxRun[tid] = -3.0e38f; sSumRun[tid] = 0.0f; }
    for (int i = tid; i < 32*D/4; i += 256)
        reinterpret_cast<float4*>(sK)[i] = reinterpret_cast<const float4*>(Mh)[i];
    __syncthreads();

    #pragma unroll
    for (int kk = 0; kk < 4; ++kk) {
        int p = tid + kk*256;
        int n = p >> 5, g = p & 31;
        const float* qrow = qb + (size_t)(nt*32 + n)*D;
        float acc[6] = {0,0,0,0,0,0};
        for (int f = 0; f < 32; ++f) {
            const float* qf = qrow + f*6;
            const float* mf = sK + f*D + g*6;
            #pragma unroll
            for (int z = 0; z < 3; ++z) {
                float q0 = qf[2*z], q1 = qf[2*z+1];
                float m0 = mf[2*z], m1 = mf[2*z+1];
                acc[2*z]   += q0*m0 - q1*m1;
                acc[2*z+1] += q1*m0 + q0*m1;
            }
        }
        #pragma unroll
        for (int j = 0; j < 6; ++j) sQM[n*196 + g*6 + j] = acc[j];
    }

    const int gn = tid >> 5;
    const int cg = tid & 31;
    const int cbase = cg*6;
    float vacc[4][6];
    #pragma unroll
    for (int a = 0; a < 4; ++a)
        #pragma unroll
        for (int b = 0; b < 6; ++b) vacc[a][b] = 0.0f;

    const int txm = tid & 15, tyn = tid >> 4;

    for (int mt = 0; mt < 32; ++mt) {
        __syncthreads();
        for (int i = tid; i < 32*(D/4); i += 256) {
            int row = i / (D/4), j = i - row*(D/4);
            float4 v = reinterpret_cast<const float4*>(kb + (size_t)(mt*32 + row)*D)[j];
            *reinterpret_cast<float4*>(&sK[row*196 + j*4]) = v;
        }
        __syncthreads();

        float a00=0,a01=0,a10=0,a11=0;
        {
            const float* q0p = &sQM[tyn*196];
            const float* q1p = &sQM[(tyn+16)*196];
            const float* k0p = &sK[txm*196];
            const float* k1p = &sK[(txm+16)*196];
            for (int k = 0; k < D; k += 4) {
                float4 qa = *reinterpret_cast<const float4*>(q0p+k);
                float4 qc = *reinterpret_cast<const float4*>(q1p+k);
                float4 ka = *reinterpret_cast<const float4*>(k0p+k);
                float4 kc = *reinterpret_cast<const float4*>(k1p+k);
                a00 += qa.x*ka.x + qa.y*ka.y + qa.z*ka.z + qa.w*ka.w;
                a01 += qa.x*kc.x + qa.y*kc.y + qa.z*kc.z + qa.w*kc.w;
                a10 += qc.x*ka.x + qc.y*ka.y + qc.z*ka.z + qc.w*ka.w;
                a11 += qc.x*kc.x + qc.y*kc.y + qc.z*kc.z + qc.w*kc.w;
            }
        }
        sS[tyn*33 + txm]          = a00;
        sS[tyn*33 + txm+16]       = a01;
        sS[(tyn+16)*33 + txm]     = a10;
        sS[(tyn+16)*33 + txm+16]  = a11;
        __syncthreads();

        const int srow = tid >> 3, sj = tid & 7;
        {
            const float* r = &sS[srow*33];
            float mx = fmaxf(fmaxf(r[sj], r[sj+8]), fmaxf(r[sj+16], r[sj+24]));
            sTmp[srow*8 + sj] = mx;
        }
        __syncthreads();
        if (tid < 32) {
            float mx = sTmp[tid*8];
            #pragma unroll
            for (int j = 1; j < 8; ++j) mx = fmaxf(mx, sTmp[tid*8+j]);
            float om = sMaxRun[tid];
            float nm = fmaxf(om, mx);
            sR[tid] = __expf(om - nm);
            sMaxRun[tid] = nm;
        }
        __syncthreads();
        {
            float nm = sMaxRun[srow];
            float* r = &sS[srow*33];
            float p0 = __expf(r[sj]    - nm);
            float p1 = __expf(r[sj+8]  - nm);
            float p2 = __expf(r[sj+16] - nm);
            float p3 = __expf(r[sj+24] - nm);
            r[sj] = p0; r[sj+8] = p1; r[sj+16] = p2; r[sj+24] = p3;
            sTmp[srow*8+sj] = p0+p1+p2+p3;
        }
        __syncthreads();
        if (tid < 32) {
            float s = 0.0f;
            #pragma unroll
            for (int j = 0; j < 8; ++j) s += sTmp[tid*8+j];
            sSumRun[tid] = sSumRun[tid]*sR[tid] + s;
        }
        {
            float r0 = sR[gn*4+0], r1 = sR[gn*4+1], r2 = sR[gn*4+2], r3 = sR[gn*4+3];
            #pragma unroll
            for (int b = 0; b < 6; ++b) { vacc[0][b]*=r0; vacc[1][b]*=r1; vacc[2][b]*=r2; vacc[3][b]*=r3; }
            for (int m = 0; m < 32; ++m) {
                float p0 = sS[(gn*4+0)*33+m];
                float p1 = sS[(gn*4+1)*33+m];
                float p2 = sS[(gn*4+2)*33+m];
                float p3 = sS[(gn*4+3)*33+m];
                const float* kr = &sK[m*196 + cbase];
                #pragma unroll
                for (int b = 0; b < 6; ++b) {
                    float kv = kr[b];
                    vacc[0][b] += p0*kv;
                    vacc[1][b] += p1*kv;
                    vacc[2][b] += p2*kv;
                    vacc[3][b] += p3*kv;
                }
            }
        }
    }

    __syncthreads();
    {
        float i0 = 1.0f/sSumRun[gn*4+0], i1 = 1.0f/sSumRun[gn*4+1];
        float i2 = 1.0f/sSumRun[gn*4+2], i3 = 1.0f/sSumRun[gn*4+3];
        #pragma unroll
        for (int b = 0; b < 6; ++b) {
            sQM[(gn*4+0)*196 + cbase + b] = vacc[0][b]*i0;
            sQM[(gn*4+1)*196 + cbase + b] = vacc[1][b]*i1;
            sQM[(gn*4+2)*196 + cbase + b] = vacc[2][b]*i2;
            sQM[(gn*4+3)*196 + cbase + b] = vacc[3][b]*i3;
        }
    }
    for (int i = tid; i < 32*D/4; i += 256)
        reinterpret_cast<float4*>(sK)[i] = reinterpret_cast<const float4*>(Ah)[i];
    __syncthreads();

    #pragma unroll
    for (int kk = 0; kk < 4; ++kk) {
        int p = tid + kk*256;
        int n = p >> 5, g = p & 31;
        float acc[6] = {0,0,0,0,0,0};
        const float* vb = &sQM[n*196];
        const float* ab = &sK[g*D];
        for (int f = 0; f < 32; ++f) {
            const float* vf = vb + f*6;
            const float* af = ab + f*6;
            #pragma unroll
            for (int z = 0; z < 3; ++z) {
                float V0 = vf[2*z], V1 = vf[2*z+1];
                float A0 = af[2*z], A1 = af[2*z+1];
                acc[2*z]   += A0*V0 - A1*V1;
                acc[2*z+1] += A0*V1 + A1*V0;
            }
        }
        float* op = ob + (size_t)(nt*32 + n)*D + g*6;
        #pragma unroll
        for (int j = 0; j < 6; ++j) atomicAdd(op + j, acc[j]);
    }
}

extern "C" void kernel_launch(void* const* d_in, const int* in_sizes, int n_in,
                              void* d_out, int out_size, void* d_ws, size_t ws_size,
                              hipStream_t stream) {
    const float* x   = (const float*)d_in[0];
    const float* Muu = (const float*)d_in[1];
    const float* Mdd = (const float*)d_in[2];
    const float* Mud = (const float*)d_in[3];
    const float* Mdu = (const float*)d_in[4];
    const float* Auu = (const float*)d_in[5];
    const float* Add = (const float*)d_in[6];
    const float* Aud = (const float*)d_in[7];
    const float* Adu = (const float*)d_in[8];
    float* outp = (float*)d_out;

    if (ws_size >= WS_NEED) {
        char* ws = (char*)d_ws;
        u16* xh  = (u16*)(ws + XH_OFF);
        u16* xl  = (u16*)(ws + XL_OFF);
        u16* xT  = (u16*)(ws + XT_OFF);
        u16* wtp = (u16*)(ws + WTP_OFF);
        u16* mth = (u16*)(ws + MTH_OFF);
        u16* mtl = (u16*)(ws + MTL_OFF);
        u16* qfh = (u16*)(ws + QFH_OFF);
        u16* qfl = (u16*)(ws + QFL_OFF);
        u16* y   = (u16*)(ws + Y_OFF);

        prep_x<<<768, 512, 0, stream>>>(x, xh, xl, xT);
        prep_wm<<<4608, 512, 0, stream>>>(Muu, Mdd, Mud, Mdu,
                                          Auu, Add, Aud, Adu, wtp, mth, mtl);
        prep_qmf<<<dim3(8, 16, 4), 256, 0, stream>>>(xh, xl, mth, mtl, qfh, qfl);
        attn_mfma<<<dim3(8, 16, 4), 256, 0, stream>>>(xh, xl, xT, wtp, qfh, qfl, y);
        reduce_y<<<96, 512, 0, stream>>>(y, outp);
    } else {
        (void)hipMemsetAsync(d_out, 0, (size_t)out_size * sizeof(float), stream);
        attn_fused_fb<<<dim3(32, 16, 4), 256, 0, stream>>>(x, Muu, Mdd, Mud, Mdu,
                                                           Auu, Add, Aud, Adu, outp);
    }
}

// Round 7
// 232.358 us; speedup vs baseline: 1.9841x; 1.9841x over previous
//
#include <hip/hip_runtime.h>
#include <hip/hip_bf16.h>

typedef unsigned short u16;
typedef unsigned int   u32;
typedef short  s16x8  __attribute__((ext_vector_type(8)));
typedef float  f32x16 __attribute__((ext_vector_type(16)));

#define HEADS 16
#define D     192
#define NUP   1024

// ---- workspace layout (bytes) ----
#define XB       (2048ull*192*2)               // 786432
#define XH_OFF   0ull
#define XL_OFF   (XH_OFF + XB)
#define XT_OFF   (XL_OFF + XB)
#define WM_BYTES (64ull*192*192*2)             // 4718592
#define WTP_OFF  (XT_OFF + XB)
#define MTH_OFF  (WTP_OFF + WM_BYTES)
#define MTL_OFF  (MTH_OFF + WM_BYTES)
#define QM_BYTES (64ull*1024*192*2)            // 25165824 (bf16)
#define QMH_OFF  (MTL_OFF + WM_BYTES)
#define QML_OFF  (QMH_OFF + QM_BYTES)
#define Y_BYTES  (64ull*1024*192*2)            // 25165824 (bf16)
#define Y_OFF    (QML_OFF + QM_BYTES)
#define WS_NEED  (Y_OFF + Y_BYTES)             // 92012544

__device__ __forceinline__ u16 f2bf(float v) {
    __hip_bfloat16 b = __float2bfloat16(v);
    return __builtin_bit_cast(u16, b);
}
__device__ __forceinline__ u32 pk2bf(float a, float b) {
    return (u32)f2bf(a) | ((u32)f2bf(b) << 16);
}
__device__ __forceinline__ float bf2f(u16 v) {
    return __builtin_bit_cast(float, (u32)v << 16);
}

// =====================================================================
// Prep A: x -> xh,xl (row-major [2048][192]) and xT ([64 tiles][192][32], hi)
// =====================================================================
__global__ __launch_bounds__(512)
void prep_x(const float* __restrict__ x, u16* __restrict__ xh,
            u16* __restrict__ xl, u16* __restrict__ xT)
{
    int i = blockIdx.x*512 + threadIdx.x;      // < 2048*192
    float v = x[i];
    int n = i / D, d = i - n*D;
    u16 hi = f2bf(v);
    xh[i] = hi;
    xl[i] = f2bf(v - bf2f(hi));
    xT[(size_t)(n >> 5)*6144 + d*32 + (n & 31)] = hi;
}

// =====================================================================
// Prep B: frag-permuted WT (from A, hi only) and MT hi/lo (from M).
// Logical: T[th][dout=(g,z,b0)][din=(f,z2,b1)], z2==z else 0:
//   b0==0: b1==0 -> +S0, b1==1 -> -S1 ;  b0==1: b1==0 -> +S1, b1==1 -> +S0
// where S = A[h][g][f][z][:] for WT, S = M[h][f][g][z][:] for MT.
// Stored permuted: [((th*6+ob)*12+ks)*64 + g32*32 + l31]*8 + j
// =====================================================================
__global__ __launch_bounds__(512)
void prep_wm(const float* __restrict__ Muu, const float* __restrict__ Mdd,
             const float* __restrict__ Mud, const float* __restrict__ Mdu,
             const float* __restrict__ Auu, const float* __restrict__ Add,
             const float* __restrict__ Aud, const float* __restrict__ Adu,
             u16* __restrict__ wtp, u16* __restrict__ mth, u16* __restrict__ mtl)
{
    int idx = blockIdx.x*512 + threadIdx.x;    // < 64*36864
    int th = idx / 36864, r = idx - th*36864;
    int dout = r / 192, din = r - dout*192;
    int t = th >> 4, h = th & 15;
    const float* Ap = (t==0)?Auu:(t==1)?Aud:(t==2)?Add:Adu;
    const float* Mp = (t==0)?Muu:(t==1)?Mud:(t==2)?Mdd:Mdu;
    int g = dout / 6, zc = dout - g*6, z = zc >> 1, b0 = zc & 1;
    int f = din / 6,  zb = din - f*6,  z2 = zb >> 1, b1 = zb & 1;

    float wv = 0.0f, mv = 0.0f;
    if (z2 == z) {
        const float* a = Ap + (((size_t)h*32 + g)*32 + f)*6 + z*2;
        float A0 = a[0], A1 = a[1];
        wv = (b0 == 0) ? (b1 == 0 ? A0 : -A1) : (b1 == 0 ? A1 : A0);
        const float* m = Mp + (((size_t)h*32 + f)*32 + g)*6 + z*2;
        float M0 = m[0], M1 = m[1];
        mv = (b0 == 0) ? (b1 == 0 ? M0 : -M1) : (b1 == 0 ? M1 : M0);
    }
    int ob = dout >> 5, l31 = dout & 31;
    int ks = din >> 4, kr = din & 15, g32 = kr >> 3, j = kr & 7;
    size_t pidx = ((((size_t)th*6 + ob)*12 + ks)*64 + g32*32 + l31)*8 + j;
    wtp[pidx] = f2bf(wv);
    u16 mh = f2bf(mv);
    mth[pidx] = mh;
    mtl[pidx] = f2bf(mv - bf2f(mh));
}

// =====================================================================
// helper: assemble B-fragment (32x32x16) from 4 packed-pair u32s in
// D-frag order (m = (r&3)+8*(r>>2)+4*(lane>>5)) via half-swap
// =====================================================================
__device__ __forceinline__ s16x8 make_bfrag(u32 q0, u32 q1, u32 q2, u32 q3, bool hi) {
    u32 s0 = (u32)__shfl_xor((int)q0, 32);
    u32 s1 = (u32)__shfl_xor((int)q1, 32);
    u32 s2 = (u32)__shfl_xor((int)q2, 32);
    u32 s3 = (u32)__shfl_xor((int)q3, 32);
    uint4 w;
    w.x = hi ? s2 : q0;  w.y = hi ? s3 : q1;
    w.z = hi ? q2 : s0;  w.w = hi ? q3 : s1;
    return __builtin_bit_cast(s16x8, w);
}

// =====================================================================
// Prep C: QM via MFMA, written to R2's row layout qm[th][n][192] hi/lo.
// D-fragment row formula (measured m32 C/D): col=l31, row=(r&3)+8*(r>>2)+4*g32.
// Per (ob,q2): 4 consecutive u16 cols -> one 8B write.
// =====================================================================
__global__ __launch_bounds__(256, 2)
void prep_qmf2(const u16* __restrict__ xh_g, const u16* __restrict__ xl_g,
               const u16* __restrict__ mth_g, const u16* __restrict__ mtl_g,
               u16* __restrict__ qmh, u16* __restrict__ qml)
{
    const int nt = blockIdx.x, h = blockIdx.y, t = blockIdx.z;
    const int tid  = threadIdx.x;
    const int lane = tid & 63;
    const int l31  = lane & 31;
    const int g32  = lane >> 5;
    const int wave = tid >> 6;
    const int th   = t*16 + h;
    const int ntile = nt*4 + wave;
    const int n0   = ntile*32;
    const int qoff = (t <= 1) ? 0 : NUP;

    s16x8 bxh[12], bxl[12];
    const u16* xrh = xh_g + (size_t)(qoff + n0 + l31)*D;
    const u16* xrl = xl_g + (size_t)(qoff + n0 + l31)*D;
    #pragma unroll
    for (int ks = 0; ks < 12; ++ks) {
        bxh[ks] = *reinterpret_cast<const s16x8*>(xrh + ks*16 + g32*8);
        bxl[ks] = *reinterpret_cast<const s16x8*>(xrl + ks*16 + g32*8);
    }
    const u16* mthb = mth_g + (size_t)th*36864;
    const u16* mtlb = mtl_g + (size_t)th*36864;
    u16* dhrow = qmh + ((size_t)th*1024 + n0 + l31)*D + 4*g32;
    u16* dlrow = qml + ((size_t)th*1024 + n0 + l31)*D + 4*g32;

    #pragma unroll
    for (int ob = 0; ob < 6; ++ob) {
        f32x16 a;
        #pragma unroll
        for (int i = 0; i < 16; ++i) a[i] = 0.0f;
        #pragma unroll
        for (int ks = 0; ks < 12; ++ks) {
            size_t fo = (((size_t)ob*12 + ks)*64 + lane)*8;
            s16x8 amh = *reinterpret_cast<const s16x8*>(mthb + fo);
            s16x8 aml = *reinterpret_cast<const s16x8*>(mtlb + fo);
            a = __builtin_amdgcn_mfma_f32_32x32x16_bf16(amh, bxh[ks], a, 0, 0, 0);
            a = __builtin_amdgcn_mfma_f32_32x32x16_bf16(amh, bxl[ks], a, 0, 0, 0);
            a = __builtin_amdgcn_mfma_f32_32x32x16_bf16(aml, bxh[ks], a, 0, 0, 0);
        }
        #pragma unroll
        for (int q2 = 0; q2 < 4; ++q2) {
            u16 hh[4], ll[4];
            #pragma unroll
            for (int rr = 0; rr < 4; ++rr) {
                float v = a[q2*4 + rr];
                u16 hi = f2bf(v);
                hh[rr] = hi;
                ll[rr] = f2bf(v - bf2f(hi));
            }
            uint2 wh, wl;
            wh.x = (u32)hh[0] | ((u32)hh[1] << 16);
            wh.y = (u32)hh[2] | ((u32)hh[3] << 16);
            wl.x = (u32)ll[0] | ((u32)ll[1] << 16);
            wl.y = (u32)ll[2] | ((u32)ll[3] << 16);
            *reinterpret_cast<uint2*>(dhrow + ob*32 + q2*8) = wh;
            *reinterpret_cast<uint2*>(dlrow + ob*32 + q2*8) = wl;
        }
    }
}

// =====================================================================
// Main fused kernel — R2 configuration: 8 waves x 32 q-rows = 256 rows
// per 512-thread block, grid (4,16,4). QM fragments resident (96 VGPR);
// loads at loop top (ld live only across one barrier). T13 + setprio.
// =====================================================================
__global__ __launch_bounds__(512, 2)
void attn_mfma(const u16* __restrict__ qmh_g, const u16* __restrict__ qml_g,
               const u16* __restrict__ xh_g,  const u16* __restrict__ xl_g,
               const u16* __restrict__ xT_g,  const u16* __restrict__ wtp_g,
               u16* __restrict__ y_g)
{
    const int nt = blockIdx.x, h = blockIdx.y, t = blockIdx.z;
    const int tid  = threadIdx.x;
    const int lane = tid & 63;
    const int l31  = lane & 31;
    const int g32  = lane >> 5;
    const int wave = tid >> 6;
    const int th   = t*16 + h;
    const int n0   = nt*256 + wave*32;
    const int koff = (t == 1 || t == 2) ? NUP : 0;   // k/v-side rows
    const int mtb  = koff >> 5;

    __shared__ u16 sXh[32*200];
    __shared__ u16 sXl[32*200];
    __shared__ u16 sXT[192*40];

    // --- QM fragments (B operand), resident in registers ---
    s16x8 qh[12], ql[12];
    {
        const u16* bh = qmh_g + ((size_t)th*1024 + n0 + l31)*D;
        const u16* bl = qml_g + ((size_t)th*1024 + n0 + l31)*D;
        #pragma unroll
        for (int ks = 0; ks < 12; ++ks) {
            qh[ks] = *reinterpret_cast<const s16x8*>(bh + ks*16 + g32*8);
            ql[ks] = *reinterpret_cast<const s16x8*>(bl + ks*16 + g32*8);
        }
    }

    f32x16 vt[6];
    #pragma unroll
    for (int ob = 0; ob < 6; ++ob)
        #pragma unroll
        for (int i = 0; i < 16; ++i) vt[ob][i] = 0.0f;

    float run_m = -3.0e38f, run_l = 0.0f;

    for (int mt = 0; mt < 32; ++mt) {
        const int krow0 = koff + mt*32;
        // A) global loads -> regs (loop top; live only across one barrier)
        uint4 ld[5];
        #pragma unroll
        for (int i = 0; i < 5; ++i) {
            int c = tid + i*512;
            if (c < 2304) {
                const u16* gp;
                if (c < 768) {
                    int rr = c/24, cc = c - rr*24;
                    gp = xh_g + (size_t)(krow0 + rr)*D + cc*8;
                } else if (c < 1536) {
                    int c2 = c - 768, rr = c2/24, cc = c2 - rr*24;
                    gp = xl_g + (size_t)(krow0 + rr)*D + cc*8;
                } else {
                    int c3 = c - 1536, dd = c3 >> 2, qq = c3 & 3;
                    gp = xT_g + (size_t)(mtb + mt)*6144 + dd*32 + qq*8;
                }
                ld[i] = *reinterpret_cast<const uint4*>(gp);
            }
        }
        __syncthreads();                        // prev compute done with LDS
        // B) write LDS (padded strides)
        #pragma unroll
        for (int i = 0; i < 5; ++i) {
            int c = tid + i*512;
            if (c < 2304) {
                u16* lp;
                if (c < 768) {
                    int rr = c/24, cc = c - rr*24;  lp = sXh + rr*200 + cc*8;
                } else if (c < 1536) {
                    int c2 = c - 768, rr = c2/24, cc = c2 - rr*24; lp = sXl + rr*200 + cc*8;
                } else {
                    int c3 = c - 1536, dd = c3 >> 2, qq = c3 & 3;  lp = sXT + dd*40 + qq*8;
                }
                *reinterpret_cast<uint4*>(lp) = ld[i];
            }
        }
        __syncthreads();

        // C) scores: St[m32][n32] = Xk * QM^T, 3-term split
        f32x16 s;
        #pragma unroll
        for (int i = 0; i < 16; ++i) s[i] = 0.0f;
        __builtin_amdgcn_s_setprio(1);
        #pragma unroll
        for (int ks = 0; ks < 12; ++ks) {
            s16x8 ah = *reinterpret_cast<const s16x8*>(sXh + l31*200 + ks*16 + g32*8);
            s16x8 al = *reinterpret_cast<const s16x8*>(sXl + l31*200 + ks*16 + g32*8);
            s = __builtin_amdgcn_mfma_f32_32x32x16_bf16(ah, qh[ks], s, 0, 0, 0);
            s = __builtin_amdgcn_mfma_f32_32x32x16_bf16(ah, ql[ks], s, 0, 0, 0);
            s = __builtin_amdgcn_mfma_f32_32x32x16_bf16(al, qh[ks], s, 0, 0, 0);
        }
        __builtin_amdgcn_s_setprio(0);

        // D) online softmax (col n = l31; lane holds 16 of 32 m values)
        float tmax = s[0];
        #pragma unroll
        for (int i = 1; i < 16; ++i) tmax = fmaxf(tmax, s[i]);
        tmax = fmaxf(tmax, __shfl_xor(tmax, 32));
        if (__any(tmax > run_m + 8.0f)) {       // defer-rescale (T13)
            float nm = fmaxf(run_m, tmax);
            float rs = __expf(run_m - nm);
            #pragma unroll
            for (int ob = 0; ob < 6; ++ob)
                #pragma unroll
                for (int i = 0; i < 16; ++i) vt[ob][i] *= rs;
            run_l *= rs;
            run_m = nm;
        }
        float p[16];
        float psum = 0.0f;
        #pragma unroll
        for (int i = 0; i < 16; ++i) { p[i] = __expf(s[i] - run_m); psum += p[i]; }
        psum += __shfl_xor(psum, 32);
        run_l += psum;

        // E) P -> bf16 B-fragments (in-register, half-swap)
        u32 q[8];
        #pragma unroll
        for (int j = 0; j < 8; ++j) q[j] = pk2bf(p[2*j], p[2*j+1]);
        s16x8 pf0 = make_bfrag(q[0], q[1], q[2], q[3], g32);
        s16x8 pf1 = make_bfrag(q[4], q[5], q[6], q[7], g32);

        // F) PV: Vt^T[d][n] += X^T * P
        __builtin_amdgcn_s_setprio(1);
        #pragma unroll
        for (int ob = 0; ob < 6; ++ob) {
            s16x8 a0 = *reinterpret_cast<const s16x8*>(sXT + (ob*32 + l31)*40 + g32*8);
            s16x8 a1 = *reinterpret_cast<const s16x8*>(sXT + (ob*32 + l31)*40 + 16 + g32*8);
            vt[ob] = __builtin_amdgcn_mfma_f32_32x32x16_bf16(a0, pf0, vt[ob], 0, 0, 0);
            vt[ob] = __builtin_amdgcn_mfma_f32_32x32x16_bf16(a1, pf1, vt[ob], 0, 0, 0);
        }
        __builtin_amdgcn_s_setprio(0);
    }

    // --- normalize ---
    float inv = 1.0f / run_l;
    #pragma unroll
    for (int ob = 0; ob < 6; ++ob)
        #pragma unroll
        for (int i = 0; i < 16; ++i) vt[ob][i] *= inv;

    // --- combine: Y^T[dout][n] = sum_din WT[dout][din] * Vt^T[din][n] ---
    const u16* wbase = wtp_g + (size_t)th*36864;
    f32x16 y[6];
    #pragma unroll
    for (int ob = 0; ob < 6; ++ob)
        #pragma unroll
        for (int i = 0; i < 16; ++i) y[ob][i] = 0.0f;

    #pragma unroll
    for (int ob = 0; ob < 6; ++ob) {
        u32 qq[8];
        #pragma unroll
        for (int j = 0; j < 8; ++j) qq[j] = pk2bf(vt[ob][2*j], vt[ob][2*j+1]);
        #pragma unroll
        for (int half = 0; half < 2; ++half) {
            int ks = ob*2 + half;
            s16x8 b = half ? make_bfrag(qq[4], qq[5], qq[6], qq[7], g32)
                           : make_bfrag(qq[0], qq[1], qq[2], qq[3], g32);
            #pragma unroll
            for (int ob2 = 0; ob2 < 6; ++ob2) {
                s16x8 a = *reinterpret_cast<const s16x8*>(
                    wbase + ((((size_t)ob2*12) + ks)*64 + lane)*8);
                y[ob2] = __builtin_amdgcn_mfma_f32_32x32x16_bf16(a, b, y[ob2], 0, 0, 0);
            }
        }
    }

    // --- write partial Y[t][h][n][dout] (bf16) ---
    u16* yrow = y_g + ((size_t)th*1024 + n0 + l31)*D;
    #pragma unroll
    for (int ob = 0; ob < 6; ++ob)
        #pragma unroll
        for (int rq = 0; rq < 4; ++rq) {
            uint2 v;
            v.x = pk2bf(y[ob][rq*4+0], y[ob][rq*4+1]);
            v.y = pk2bf(y[ob][rq*4+2], y[ob][rq*4+3]);
            *reinterpret_cast<uint2*>(yrow + ob*32 + rq*8 + g32*4) = v;
        }
}

// =====================================================================
// Reduce: out[p*1024+n][d] = sum_{t in pair, h} y[t][h][n][d]  (bf16 in)
// =====================================================================
__global__ __launch_bounds__(512)
void reduce_y(const u16* __restrict__ y_g, float* __restrict__ out)
{
    int gi = blockIdx.x*512 + threadIdx.x;     // < 2048*192/8
    int n = gi / 24, c = gi - n*24;
    int p = n >> 10, nn = n & 1023;
    float acc[8];
    #pragma unroll
    for (int j = 0; j < 8; ++j) acc[j] = 0.0f;
    #pragma unroll
    for (int k = 0; k < 32; ++k) {
        int tcur = p*2 + (k >> 4), hh = k & 15;
        uint4 v = *reinterpret_cast<const uint4*>(
            y_g + ((size_t)((tcur*16+hh)*1024 + nn))*D + c*8);
        u32 w[4] = {v.x, v.y, v.z, v.w};
        #pragma unroll
        for (int j = 0; j < 4; ++j) {
            acc[2*j]   += __builtin_bit_cast(float, w[j] << 16);
            acc[2*j+1] += __builtin_bit_cast(float, w[j] & 0xffff0000u);
        }
    }
    float* op = out + (size_t)n*D + c*8;
    float4 o0 = {acc[0], acc[1], acc[2], acc[3]};
    float4 o1 = {acc[4], acc[5], acc[6], acc[7]};
    *reinterpret_cast<float4*>(op)     = o0;
    *reinterpret_cast<float4*>(op + 4) = o1;
}

// =====================================================================
// Fallback (round-1 fp32 kernel) if ws too small
// =====================================================================
__global__ __launch_bounds__(256, 2)
void attn_fused_fb(const float* __restrict__ x,
                const float* __restrict__ Muu, const float* __restrict__ Mdd,
                const float* __restrict__ Mud, const float* __restrict__ Mdu,
                const float* __restrict__ Auu, const float* __restrict__ Add,
                const float* __restrict__ Aud, const float* __restrict__ Adu,
                float* __restrict__ out)
{
    const int nt  = blockIdx.x;
    const int h   = blockIdx.y;
    const int t   = blockIdx.z;
    const int tid = threadIdx.x;
    const float* qb = (t <= 1) ? x : x + (size_t)NUP*D;
    const float* kb = (t == 0 || t == 3) ? x : x + (size_t)NUP*D;
    const float* Mp = (t==0)?Muu:(t==1)?Mud:(t==2)?Mdd:Mdu;
    const float* Ap = (t==0)?Auu:(t==1)?Aud:(t==2)?Add:Adu;
    const float* Mh = Mp + (size_t)h*32*D;
    const float* Ah = Ap + (size_t)h*32*D;
    float* ob = out + ((t>=2) ? (size_t)NUP*D : 0);

    __shared__ float sK[32*196];
    __shared__ float sQM[32*196];
    __shared__ float sS[32*33];
    __shared__ float sTmp[32*8];
    __shared__ float sR[32];
    __shared__ float sMaxRun[32];
    __shared__ float sSumRun[32];

    if (tid < 32) { sMaxRun[tid] = -3.0e38f; sSumRun[tid] = 0.0f; }
    for (int i = tid; i < 32*D/4; i += 256)
        reinterpret_cast<float4*>(sK)[i] = reinterpret_cast<const float4*>(Mh)[i];
    __syncthreads();

    #pragma unroll
    for (int kk = 0; kk < 4; ++kk) {
        int p = tid + kk*256;
        int n = p >> 5, g = p & 31;
        const float* qrow = qb + (size_t)(nt*32 + n)*D;
        float acc[6] = {0,0,0,0,0,0};
        for (int f = 0; f < 32; ++f) {
            const float* qf = qrow + f*6;
            const float* mf = sK + f*D + g*6;
            #pragma unroll
            for (int z = 0; z < 3; ++z) {
                float q0 = qf[2*z], q1 = qf[2*z+1];
                float m0 = mf[2*z], m1 = mf[2*z+1];
                acc[2*z]   += q0*m0 - q1*m1;
                acc[2*z+1] += q1*m0 + q0*m1;
            }
        }
        #pragma unroll
        for (int j = 0; j < 6; ++j) sQM[n*196 + g*6 + j] = acc[j];
    }

    const int gn = tid >> 5;
    const int cg = tid & 31;
    const int cbase = cg*6;
    float vacc[4][6];
    #pragma unroll
    for (int a = 0; a < 4; ++a)
        #pragma unroll
        for (int b = 0; b < 6; ++b) vacc[a][b] = 0.0f;

    const int txm = tid & 15, tyn = tid >> 4;

    for (int mt = 0; mt < 32; ++mt) {
        __syncthreads();
        for (int i = tid; i < 32*(D/4); i += 256) {
            int row = i / (D/4), j = i - row*(D/4);
            float4 v = reinterpret_cast<const float4*>(kb + (size_t)(mt*32 + row)*D)[j];
            *reinterpret_cast<float4*>(&sK[row*196 + j*4]) = v;
        }
        __syncthreads();

        float a00=0,a01=0,a10=0,a11=0;
        {
            const float* q0p = &sQM[tyn*196];
            const float* q1p = &sQM[(tyn+16)*196];
            const float* k0p = &sK[txm*196];
            const float* k1p = &sK[(txm+16)*196];
            for (int k = 0; k < D; k += 4) {
                float4 qa = *reinterpret_cast<const float4*>(q0p+k);
                float4 qc = *reinterpret_cast<const float4*>(q1p+k);
                float4 ka = *reinterpret_cast<const float4*>(k0p+k);
                float4 kc = *reinterpret_cast<const float4*>(k1p+k);
                a00 += qa.x*ka.x + qa.y*ka.y + qa.z*ka.z + qa.w*ka.w;
                a01 += qa.x*kc.x + qa.y*kc.y + qa.z*kc.z + qa.w*kc.w;
                a10 += qc.x*ka.x + qc.y*ka.y + qc.z*ka.z + qc.w*ka.w;
                a11 += qc.x*kc.x + qc.y*kc.y + qc.z*kc.z + qc.w*kc.w;
            }
        }
        sS[tyn*33 + txm]          = a00;
        sS[tyn*33 + txm+16]       = a01;
        sS[(tyn+16)*33 + txm]     = a10;
        sS[(tyn+16)*33 + txm+16]  = a11;
        __syncthreads();

        const int srow = tid >> 3, sj = tid & 7;
        {
            const float* r = &sS[srow*33];
            float mx = fmaxf(fmaxf(r[sj], r[sj+8]), fmaxf(r[sj+16], r[sj+24]));
            sTmp[srow*8 + sj] = mx;
        }
        __syncthreads();
        if (tid < 32) {
            float mx = sTmp[tid*8];
            #pragma unroll
            for (int j = 1; j < 8; ++j) mx = fmaxf(mx, sTmp[tid*8+j]);
            float om = sMaxRun[tid];
            float nm = fmaxf(om, mx);
            sR[tid] = __expf(om - nm);
            sMaxRun[tid] = nm;
        }
        __syncthreads();
        {
            float nm = sMaxRun[srow];
            float* r = &sS[srow*33];
            float p0 = __expf(r[sj]    - nm);
            float p1 = __expf(r[sj+8]  - nm);
            float p2 = __expf(r[sj+16] - nm);
            float p3 = __expf(r[sj+24] - nm);
            r[sj] = p0; r[sj+8] = p1; r[sj+16] = p2; r[sj+24] = p3;
            sTmp[srow*8+sj] = p0+p1+p2+p3;
        }
        __syncthreads();
        if (tid < 32) {
            float s = 0.0f;
            #pragma unroll
            for (int j = 0; j < 8; ++j) s += sTmp[tid*8+j];
            sSumRun[tid] = sSumRun[tid]*sR[tid] + s;
        }
        {
            float r0 = sR[gn*4+0], r1 = sR[gn*4+1], r2 = sR[gn*4+2], r3 = sR[gn*4+3];
            #pragma unroll
            for (int b = 0; b < 6; ++b) { vacc[0][b]*=r0; vacc[1][b]*=r1; vacc[2][b]*=r2; vacc[3][b]*=r3; }
            for (int m = 0; m < 32; ++m) {
                float p0 = sS[(gn*4+0)*33+m];
                float p1 = sS[(gn*4+1)*33+m];
                float p2 = sS[(gn*4+2)*33+m];
                float p3 = sS[(gn*4+3)*33+m];
                const float* kr = &sK[m*196 + cbase];
                #pragma unroll
                for (int b = 0; b < 6; ++b) {
                    float kv = kr[b];
                    vacc[0][b] += p0*kv;
                    vacc[1][b] += p1*kv;
                    vacc[2][b] += p2*kv;
                    vacc[3][b] += p3*kv;
                }
            }
        }
    }

    __syncthreads();
    {
        float i0 = 1.0f/sSumRun[gn*4+0], i1 = 1.0f/sSumRun[gn*4+1];
        float i2 = 1.0f/sSumRun[gn*4+2], i3 = 1.0f/sSumRun[gn*4+3];
        #pragma unroll
        for (int b = 0; b < 6; ++b) {
            sQM[(gn*4+0)*196 + cbase + b] = vacc[0][b]*i0;
            sQM[(gn*4+1)*196 + cbase + b] = vacc[1][b]*i1;
            sQM[(gn*4+2)*196 + cbase + b] = vacc[2][b]*i2;
            sQM[(gn*4+3)*196 + cbase + b] = vacc[3][b]*i3;
        }
    }
    for (int i = tid; i < 32*D/4; i += 256)
        reinterpret_cast<float4*>(sK)[i] = reinterpret_cast<const float4*>(Ah)[i];
    __syncthreads();

    #pragma unroll
    for (int kk = 0; kk < 4; ++kk) {
        int p = tid + kk*256;
        int n = p >> 5, g = p & 31;
        float acc[6] = {0,0,0,0,0,0};
        const float* vb = &sQM[n*196];
        const float* ab = &sK[g*D];
        for (int f = 0; f < 32; ++f) {
            const float* vf = vb + f*6;
            const float* af = ab + f*6;
            #pragma unroll
            for (int z = 0; z < 3; ++z) {
                float V0 = vf[2*z], V1 = vf[2*z+1];
                float A0 = af[2*z], A1 = af[2*z+1];
                acc[2*z]   += A0*V0 - A1*V1;
                acc[2*z+1] += A0*V1 + A1*V0;
            }
        }
        float* op = ob + (size_t)(nt*32 + n)*D + g*6;
        #pragma unroll
        for (int j = 0; j < 6; ++j) atomicAdd(op + j, acc[j]);
    }
}

extern "C" void kernel_launch(void* const* d_in, const int* in_sizes, int n_in,
                              void* d_out, int out_size, void* d_ws, size_t ws_size,
                              hipStream_t stream) {
    const float* x   = (const float*)d_in[0];
    const float* Muu = (const float*)d_in[1];
    const float* Mdd = (const float*)d_in[2];
    const float* Mud = (const float*)d_in[3];
    const float* Mdu = (const float*)d_in[4];
    const float* Auu = (const float*)d_in[5];
    const float* Add = (const float*)d_in[6];
    const float* Aud = (const float*)d_in[7];
    const float* Adu = (const float*)d_in[8];
    float* outp = (float*)d_out;

    if (ws_size >= WS_NEED) {
        char* ws = (char*)d_ws;
        u16* xh  = (u16*)(ws + XH_OFF);
        u16* xl  = (u16*)(ws + XL_OFF);
        u16* xT  = (u16*)(ws + XT_OFF);
        u16* wtp = (u16*)(ws + WTP_OFF);
        u16* mth = (u16*)(ws + MTH_OFF);
        u16* mtl = (u16*)(ws + MTL_OFF);
        u16* qmh = (u16*)(ws + QMH_OFF);
        u16* qml = (u16*)(ws + QML_OFF);
        u16* y   = (u16*)(ws + Y_OFF);

        prep_x<<<768, 512, 0, stream>>>(x, xh, xl, xT);
        prep_wm<<<4608, 512, 0, stream>>>(Muu, Mdd, Mud, Mdu,
                                          Auu, Add, Aud, Adu, wtp, mth, mtl);
        prep_qmf2<<<dim3(8, 16, 4), 256, 0, stream>>>(xh, xl, mth, mtl, qmh, qml);
        attn_mfma<<<dim3(4, 16, 4), 512, 0, stream>>>(qmh, qml, xh, xl, xT, wtp, y);
        reduce_y<<<96, 512, 0, stream>>>(y, outp);
    } else {
        (void)hipMemsetAsync(d_out, 0, (size_t)out_size * sizeof(float), stream);
        attn_fused_fb<<<dim3(32, 16, 4), 256, 0, stream>>>(x, Muu, Mdd, Mud, Mdu,
                                                           Auu, Add, Aud, Adu, outp);
    }
}

// Round 8
// 175.047 us; speedup vs baseline: 2.6337x; 1.3274x over previous
//
#include <hip/hip_runtime.h>
#include <hip/hip_bf16.h>

typedef unsigned short u16;
typedef unsigned int   u32;
typedef _Float16 f16x8 __attribute__((ext_vector_type(8)));
typedef float    f32x16 __attribute__((ext_vector_type(16)));

#define HEADS 16
#define D     192
#define NUP   1024

// ---- workspace layout (bytes) ----
#define XB       (2048ull*192*2)               // 786432
#define XH_OFF   0ull
#define XL_OFF   (XH_OFF + XB)
#define XT_OFF   (XL_OFF + XB)
#define WM_BYTES (64ull*192*192*2)             // 4718592
#define WTP_OFF  (XT_OFF + XB)
#define MTH_OFF  (WTP_OFF + WM_BYTES)
#define MTL_OFF  (MTH_OFF + WM_BYTES)
#define QM_BYTES (64ull*1024*192*2)            // 25165824 (fp16)
#define QMH_OFF  (MTL_OFF + WM_BYTES)
#define QML_OFF  (QMH_OFF + QM_BYTES)
#define Y_BYTES  (64ull*1024*192*2)            // 25165824 (fp16)
#define Y_OFF    (QML_OFF + QM_BYTES)
#define WS_NEED  (Y_OFF + Y_BYTES)             // 92012544

__device__ __forceinline__ u16 f2h(float v) {
    _Float16 h = (_Float16)v;
    return __builtin_bit_cast(u16, h);
}
__device__ __forceinline__ float h2f(u16 v) {
    return (float)__builtin_bit_cast(_Float16, v);
}
__device__ __forceinline__ u32 pk2h(float a, float b) {
    return (u32)f2h(a) | ((u32)f2h(b) << 16);
}

// =====================================================================
// Prep A: x -> xh,xl fp16 (row-major [2048][192]) and xT fp16
// ([64 tiles][192][32])
// =====================================================================
__global__ __launch_bounds__(512)
void prep_x(const float* __restrict__ x, u16* __restrict__ xh,
            u16* __restrict__ xl, u16* __restrict__ xT)
{
    int i = blockIdx.x*512 + threadIdx.x;      // < 2048*192
    float v = x[i];
    int n = i / D, d = i - n*D;
    u16 hi = f2h(v);
    xh[i] = hi;
    xl[i] = f2h(v - h2f(hi));
    xT[(size_t)(n >> 5)*6144 + d*32 + (n & 31)] = hi;
}

// =====================================================================
// Prep B: frag-permuted WT (from A, fp16 single) and MT fp16 hi/lo (from M).
// Logical: T[th][dout=(g,z,b0)][din=(f,z2,b1)], z2==z else 0:
//   b0==0: b1==0 -> +S0, b1==1 -> -S1 ;  b0==1: b1==0 -> +S1, b1==1 -> +S0
// where S = A[h][g][f][z][:] for WT, S = M[h][f][g][z][:] for MT.
// Stored permuted: [((th*6+ob)*12+ks)*64 + g32*32 + l31]*8 + j
// =====================================================================
__global__ __launch_bounds__(512)
void prep_wm(const float* __restrict__ Muu, const float* __restrict__ Mdd,
             const float* __restrict__ Mud, const float* __restrict__ Mdu,
             const float* __restrict__ Auu, const float* __restrict__ Add,
             const float* __restrict__ Aud, const float* __restrict__ Adu,
             u16* __restrict__ wtp, u16* __restrict__ mth, u16* __restrict__ mtl)
{
    int idx = blockIdx.x*512 + threadIdx.x;    // < 64*36864
    int th = idx / 36864, r = idx - th*36864;
    int dout = r / 192, din = r - dout*192;
    int t = th >> 4, h = th & 15;
    const float* Ap = (t==0)?Auu:(t==1)?Aud:(t==2)?Add:Adu;
    const float* Mp = (t==0)?Muu:(t==1)?Mud:(t==2)?Mdd:Mdu;
    int g = dout / 6, zc = dout - g*6, z = zc >> 1, b0 = zc & 1;
    int f = din / 6,  zb = din - f*6,  z2 = zb >> 1, b1 = zb & 1;

    float wv = 0.0f, mv = 0.0f;
    if (z2 == z) {
        const float* a = Ap + (((size_t)h*32 + g)*32 + f)*6 + z*2;
        float A0 = a[0], A1 = a[1];
        wv = (b0 == 0) ? (b1 == 0 ? A0 : -A1) : (b1 == 0 ? A1 : A0);
        const float* m = Mp + (((size_t)h*32 + f)*32 + g)*6 + z*2;
        float M0 = m[0], M1 = m[1];
        mv = (b0 == 0) ? (b1 == 0 ? M0 : -M1) : (b1 == 0 ? M1 : M0);
    }
    int ob = dout >> 5, l31 = dout & 31;
    int ks = din >> 4, kr = din & 15, g32 = kr >> 3, j = kr & 7;
    size_t pidx = ((((size_t)th*6 + ob)*12 + ks)*64 + g32*32 + l31)*8 + j;
    wtp[pidx] = f2h(wv);
    u16 mh = f2h(mv);
    mth[pidx] = mh;
    mtl[pidx] = f2h(mv - h2f(mh));
}

// =====================================================================
// helper: assemble B-fragment (32x32x16) from 4 packed-pair u32s in
// D-frag order (m = (r&3)+8*(r>>2)+4*(lane>>5)) via half-swap
// =====================================================================
__device__ __forceinline__ f16x8 make_bfrag(u32 q0, u32 q1, u32 q2, u32 q3, bool hi) {
    u32 s0 = (u32)__shfl_xor((int)q0, 32);
    u32 s1 = (u32)__shfl_xor((int)q1, 32);
    u32 s2 = (u32)__shfl_xor((int)q2, 32);
    u32 s3 = (u32)__shfl_xor((int)q3, 32);
    uint4 w;
    w.x = hi ? s2 : q0;  w.y = hi ? s3 : q1;
    w.z = hi ? q2 : s0;  w.w = hi ? q3 : s1;
    return __builtin_bit_cast(f16x8, w);
}

// =====================================================================
// Prep C: QM via MFMA (3-term fp16 split), written to row layout
// qm[th][n][192] hi/lo fp16. D-frag row formula: col=l31,
// row=(r&3)+8*(r>>2)+4*g32; per (ob,q2) 4 consecutive cols -> 8B write.
// =====================================================================
__global__ __launch_bounds__(256, 2)
void prep_qmf2(const u16* __restrict__ xh_g, const u16* __restrict__ xl_g,
               const u16* __restrict__ mth_g, const u16* __restrict__ mtl_g,
               u16* __restrict__ qmh, u16* __restrict__ qml)
{
    const int nt = blockIdx.x, h = blockIdx.y, t = blockIdx.z;
    const int tid  = threadIdx.x;
    const int lane = tid & 63;
    const int l31  = lane & 31;
    const int g32  = lane >> 5;
    const int wave = tid >> 6;
    const int th   = t*16 + h;
    const int ntile = nt*4 + wave;
    const int n0   = ntile*32;
    const int qoff = (t <= 1) ? 0 : NUP;

    f16x8 bxh[12], bxl[12];
    const u16* xrh = xh_g + (size_t)(qoff + n0 + l31)*D;
    const u16* xrl = xl_g + (size_t)(qoff + n0 + l31)*D;
    #pragma unroll
    for (int ks = 0; ks < 12; ++ks) {
        bxh[ks] = *reinterpret_cast<const f16x8*>(xrh + ks*16 + g32*8);
        bxl[ks] = *reinterpret_cast<const f16x8*>(xrl + ks*16 + g32*8);
    }
    const u16* mthb = mth_g + (size_t)th*36864;
    const u16* mtlb = mtl_g + (size_t)th*36864;
    u16* dhrow = qmh + ((size_t)th*1024 + n0 + l31)*D + 4*g32;
    u16* dlrow = qml + ((size_t)th*1024 + n0 + l31)*D + 4*g32;

    #pragma unroll
    for (int ob = 0; ob < 6; ++ob) {
        f32x16 a;
        #pragma unroll
        for (int i = 0; i < 16; ++i) a[i] = 0.0f;
        #pragma unroll
        for (int ks = 0; ks < 12; ++ks) {
            size_t fo = (((size_t)ob*12 + ks)*64 + lane)*8;
            f16x8 amh = *reinterpret_cast<const f16x8*>(mthb + fo);
            f16x8 aml = *reinterpret_cast<const f16x8*>(mtlb + fo);
            a = __builtin_amdgcn_mfma_f32_32x32x16_f16(amh, bxh[ks], a, 0, 0, 0);
            a = __builtin_amdgcn_mfma_f32_32x32x16_f16(amh, bxl[ks], a, 0, 0, 0);
            a = __builtin_amdgcn_mfma_f32_32x32x16_f16(aml, bxh[ks], a, 0, 0, 0);
        }
        #pragma unroll
        for (int q2 = 0; q2 < 4; ++q2) {
            u16 hh[4], ll[4];
            #pragma unroll
            for (int rr = 0; rr < 4; ++rr) {
                float v = a[q2*4 + rr];
                u16 hi = f2h(v);
                hh[rr] = hi;
                ll[rr] = f2h(v - h2f(hi));
            }
            uint2 wh, wl;
            wh.x = (u32)hh[0] | ((u32)hh[1] << 16);
            wh.y = (u32)hh[2] | ((u32)hh[3] << 16);
            wl.x = (u32)ll[0] | ((u32)ll[1] << 16);
            wl.y = (u32)ll[2] | ((u32)ll[3] << 16);
            *reinterpret_cast<uint2*>(dhrow + ob*32 + q2*8) = wh;
            *reinterpret_cast<uint2*>(dlrow + ob*32 + q2*8) = wl;
        }
    }
}

// =====================================================================
// Main fused kernel — 8 waves x 32 q-rows, 512 threads, grid (4,16,4).
// fp16, 2-term scores (24 MFMA) + PV (12 MFMA) per iter. LDS double-
// buffered, ONE barrier per iteration: stage(t+1) after compute(t).
// =====================================================================
__global__ __launch_bounds__(512, 2)
void attn_mfma(const u16* __restrict__ qmh_g, const u16* __restrict__ qml_g,
               const u16* __restrict__ xh_g,  const u16* __restrict__ xT_g,
               const u16* __restrict__ wtp_g, u16* __restrict__ y_g)
{
    const int nt = blockIdx.x, h = blockIdx.y, t = blockIdx.z;
    const int tid  = threadIdx.x;
    const int lane = tid & 63;
    const int l31  = lane & 31;
    const int g32  = lane >> 5;
    const int wave = tid >> 6;
    const int th   = t*16 + h;
    const int n0   = nt*256 + wave*32;
    const int koff = (t == 1 || t == 2) ? NUP : 0;   // k/v-side rows
    const int mtb  = koff >> 5;

    __shared__ u16 sXh[2][32*200];
    __shared__ u16 sXT[2][192*40];

    // --- QM fragments (B operand), resident in registers ---
    f16x8 qh[12], ql[12];
    {
        const u16* bh = qmh_g + ((size_t)th*1024 + n0 + l31)*D;
        const u16* bl = qml_g + ((size_t)th*1024 + n0 + l31)*D;
        #pragma unroll
        for (int ks = 0; ks < 12; ++ks) {
            qh[ks] = *reinterpret_cast<const f16x8*>(bh + ks*16 + g32*8);
            ql[ks] = *reinterpret_cast<const f16x8*>(bl + ks*16 + g32*8);
        }
    }

    f32x16 vt[6];
    #pragma unroll
    for (int ob = 0; ob < 6; ++ob)
        #pragma unroll
        for (int i = 0; i < 16; ++i) vt[ob][i] = 0.0f;

    float run_m = -3.0e38f, run_l = 0.0f;

    // staging: 1536 chunks of 8 u16: 768 xh-rows + 768 xT
    uint4 ld[3];
    auto load_tile = [&](int mt) {
        const int krow0 = koff + mt*32;
        #pragma unroll
        for (int i = 0; i < 3; ++i) {
            int c = tid + i*512;
            const u16* gp;
            if (c < 768) {
                int rr = c/24, cc = c - rr*24;
                gp = xh_g + (size_t)(krow0 + rr)*D + cc*8;
            } else {
                int c3 = c - 768, dd = c3 >> 2, qq = c3 & 3;
                gp = xT_g + (size_t)(mtb + mt)*6144 + dd*32 + qq*8;
            }
            ld[i] = *reinterpret_cast<const uint4*>(gp);
        }
    };
    auto store_tile = [&](int buf) {
        #pragma unroll
        for (int i = 0; i < 3; ++i) {
            int c = tid + i*512;
            u16* lp;
            if (c < 768) {
                int rr = c/24, cc = c - rr*24;  lp = &sXh[buf][rr*200 + cc*8];
            } else {
                int c3 = c - 768, dd = c3 >> 2, qq = c3 & 3;  lp = &sXT[buf][dd*40 + qq*8];
            }
            *reinterpret_cast<uint4*>(lp) = ld[i];
        }
    };

    // prologue: stage tile 0 into buf 0
    load_tile(0);
    store_tile(0);
    __syncthreads();

    for (int mt = 0; mt < 32; ++mt) {
        const int cur = mt & 1;
        if (mt < 31) load_tile(mt+1);   // issue early; lands during compute

        // C) scores: St[m32][n32] = Xk * QM^T, fp16 2-term
        f32x16 s;
        #pragma unroll
        for (int i = 0; i < 16; ++i) s[i] = 0.0f;
        __builtin_amdgcn_s_setprio(1);
        #pragma unroll
        for (int ks = 0; ks < 12; ++ks) {
            f16x8 ah = *reinterpret_cast<const f16x8*>(&sXh[cur][l31*200 + ks*16 + g32*8]);
            s = __builtin_amdgcn_mfma_f32_32x32x16_f16(ah, qh[ks], s, 0, 0, 0);
            s = __builtin_amdgcn_mfma_f32_32x32x16_f16(ah, ql[ks], s, 0, 0, 0);
        }
        __builtin_amdgcn_s_setprio(0);

        // D) online softmax (col n = l31; lane holds 16 of 32 m values)
        float tmax = s[0];
        #pragma unroll
        for (int i = 1; i < 16; ++i) tmax = fmaxf(tmax, s[i]);
        tmax = fmaxf(tmax, __shfl_xor(tmax, 32));
        if (__any(tmax > run_m + 8.0f)) {       // defer-rescale (T13)
            float nm = fmaxf(run_m, tmax);
            float rs = __expf(run_m - nm);
            #pragma unroll
            for (int ob = 0; ob < 6; ++ob)
                #pragma unroll
                for (int i = 0; i < 16; ++i) vt[ob][i] *= rs;
            run_l *= rs;
            run_m = nm;
        }
        float p[16];
        float psum = 0.0f;
        #pragma unroll
        for (int i = 0; i < 16; ++i) { p[i] = __expf(s[i] - run_m); psum += p[i]; }
        psum += __shfl_xor(psum, 32);
        run_l += psum;

        // E) P -> fp16 B-fragments (in-register, half-swap)
        u32 q[8];
        #pragma unroll
        for (int j = 0; j < 8; ++j) q[j] = pk2h(p[2*j], p[2*j+1]);
        f16x8 pf0 = make_bfrag(q[0], q[1], q[2], q[3], g32);
        f16x8 pf1 = make_bfrag(q[4], q[5], q[6], q[7], g32);

        // F) PV: Vt^T[d][n] += X^T * P
        __builtin_amdgcn_s_setprio(1);
        #pragma unroll
        for (int ob = 0; ob < 6; ++ob) {
            f16x8 a0 = *reinterpret_cast<const f16x8*>(&sXT[cur][(ob*32 + l31)*40 + g32*8]);
            f16x8 a1 = *reinterpret_cast<const f16x8*>(&sXT[cur][(ob*32 + l31)*40 + 16 + g32*8]);
            vt[ob] = __builtin_amdgcn_mfma_f32_32x32x16_f16(a0, pf0, vt[ob], 0, 0, 0);
            vt[ob] = __builtin_amdgcn_mfma_f32_32x32x16_f16(a1, pf1, vt[ob], 0, 0, 0);
        }
        __builtin_amdgcn_s_setprio(0);

        // G) stage next tile into the other buffer; single barrier
        if (mt < 31) store_tile(cur ^ 1);
        __syncthreads();
    }

    // --- normalize ---
    float inv = 1.0f / run_l;
    #pragma unroll
    for (int ob = 0; ob < 6; ++ob)
        #pragma unroll
        for (int i = 0; i < 16; ++i) vt[ob][i] *= inv;

    // --- combine: Y^T[dout][n] = sum_din WT[dout][din] * Vt^T[din][n] ---
    const u16* wbase = wtp_g + (size_t)th*36864;
    f32x16 y[6];
    #pragma unroll
    for (int ob = 0; ob < 6; ++ob)
        #pragma unroll
        for (int i = 0; i < 16; ++i) y[ob][i] = 0.0f;

    #pragma unroll
    for (int ob = 0; ob < 6; ++ob) {
        u32 qq[8];
        #pragma unroll
        for (int j = 0; j < 8; ++j) qq[j] = pk2h(vt[ob][2*j], vt[ob][2*j+1]);
        #pragma unroll
        for (int half = 0; half < 2; ++half) {
            int ks = ob*2 + half;
            f16x8 b = half ? make_bfrag(qq[4], qq[5], qq[6], qq[7], g32)
                           : make_bfrag(qq[0], qq[1], qq[2], qq[3], g32);
            #pragma unroll
            for (int ob2 = 0; ob2 < 6; ++ob2) {
                f16x8 a = *reinterpret_cast<const f16x8*>(
                    wbase + ((((size_t)ob2*12) + ks)*64 + lane)*8);
                y[ob2] = __builtin_amdgcn_mfma_f32_32x32x16_f16(a, b, y[ob2], 0, 0, 0);
            }
        }
    }

    // --- write partial Y[t][h][n][dout] (fp16) ---
    u16* yrow = y_g + ((size_t)th*1024 + n0 + l31)*D;
    #pragma unroll
    for (int ob = 0; ob < 6; ++ob)
        #pragma unroll
        for (int rq = 0; rq < 4; ++rq) {
            uint2 v;
            v.x = pk2h(y[ob][rq*4+0], y[ob][rq*4+1]);
            v.y = pk2h(y[ob][rq*4+2], y[ob][rq*4+3]);
            *reinterpret_cast<uint2*>(yrow + ob*32 + rq*8 + g32*4) = v;
        }
}

// =====================================================================
// Reduce: out[p*1024+n][d] = sum_{t in pair, h} y[t][h][n][d]  (fp16 in)
// =====================================================================
__global__ __launch_bounds__(512)
void reduce_y(const u16* __restrict__ y_g, float* __restrict__ out)
{
    int gi = blockIdx.x*512 + threadIdx.x;     // < 2048*192/8
    int n = gi / 24, c = gi - n*24;
    int p = n >> 10, nn = n & 1023;
    float acc[8];
    #pragma unroll
    for (int j = 0; j < 8; ++j) acc[j] = 0.0f;
    #pragma unroll
    for (int k = 0; k < 32; ++k) {
        int tcur = p*2 + (k >> 4), hh = k & 15;
        uint4 v = *reinterpret_cast<const uint4*>(
            y_g + ((size_t)((tcur*16+hh)*1024 + nn))*D + c*8);
        u32 w[4] = {v.x, v.y, v.z, v.w};
        #pragma unroll
        for (int j = 0; j < 4; ++j) {
            acc[2*j]   += h2f((u16)(w[j] & 0xffffu));
            acc[2*j+1] += h2f((u16)(w[j] >> 16));
        }
    }
    float* op = out + (size_t)n*D + c*8;
    float4 o0 = {acc[0], acc[1], acc[2], acc[3]};
    float4 o1 = {acc[4], acc[5], acc[6], acc[7]};
    *reinterpret_cast<float4*>(op)     = o0;
    *reinterpret_cast<float4*>(op + 4) = o1;
}

// =====================================================================
// Fallback (round-1 fp32 kernel) if ws too small
// =====================================================================
__global__ __launch_bounds__(256, 2)
void attn_fused_fb(const float* __restrict__ x,
                const float* __restrict__ Muu, const float* __restrict__ Mdd,
                const float* __restrict__ Mud, const float* __restrict__ Mdu,
                const float* __restrict__ Auu, const float* __restrict__ Add,
                const float* __restrict__ Aud, const float* __restrict__ Adu,
                float* __restrict__ out)
{
    const int nt  = blockIdx.x;
    const int h   = blockIdx.y;
    const int t   = blockIdx.z;
    const int tid = threadIdx.x;
    const float* qb = (t <= 1) ? x : x + (size_t)NUP*D;
    const float* kb = (t == 0 || t == 3) ? x : x + (size_t)NUP*D;
    const float* Mp = (t==0)?Muu:(t==1)?Mud:(t==2)?Mdd:Mdu;
    const float* Ap = (t==0)?Auu:(t==1)?Aud:(t==2)?Add:Adu;
    const float* Mh = Mp + (size_t)h*32*D;
    const float* Ah = Ap + (size_t)h*32*D;
    float* ob = out + ((t>=2) ? (size_t)NUP*D : 0);

    __shared__ float sK[32*196];
    __shared__ float sQM[32*196];
    __shared__ float sS[32*33];
    __shared__ float sTmp[32*8];
    __shared__ float sR[32];
    __shared__ float sMaxRun[32];
    __shared__ float sSumRun[32];

    if (tid < 32) { sMaxRun[tid] = -3.0e38f; sSumRun[tid] = 0.0f; }
    for (int i = tid; i < 32*D/4; i += 256)
        reinterpret_cast<float4*>(sK)[i] = reinterpret_cast<const float4*>(Mh)[i];
    __syncthreads();

    #pragma unroll
    for (int kk = 0; kk < 4; ++kk) {
        int p = tid + kk*256;
        int n = p >> 5, g = p & 31;
        const float* qrow = qb + (size_t)(nt*32 + n)*D;
        float acc[6] = {0,0,0,0,0,0};
        for (int f = 0; f < 32; ++f) {
            const float* qf = qrow + f*6;
            const float* mf = sK + f*D + g*6;
            #pragma unroll
            for (int z = 0; z < 3; ++z) {
                float q0 = qf[2*z], q1 = qf[2*z+1];
                float m0 = mf[2*z], m1 = mf[2*z+1];
                acc[2*z]   += q0*m0 - q1*m1;
                acc[2*z+1] += q1*m0 + q0*m1;
            }
        }
        #pragma unroll
        for (int j = 0; j < 6; ++j) sQM[n*196 + g*6 + j] = acc[j];
    }

    const int gn = tid >> 5;
    const int cg = tid & 31;
    const int cbase = cg*6;
    float vacc[4][6];
    #pragma unroll
    for (int a = 0; a < 4; ++a)
        #pragma unroll
        for (int b = 0; b < 6; ++b) vacc[a][b] = 0.0f;

    const int txm = tid & 15, tyn = tid >> 4;

    for (int mt = 0; mt < 32; ++mt) {
        __syncthreads();
        for (int i = tid; i < 32*(D/4); i += 256) {
            int row = i / (D/4), j = i - row*(D/4);
            float4 v = reinterpret_cast<const float4*>(kb + (size_t)(mt*32 + row)*D)[j];
            *reinterpret_cast<float4*>(&sK[row*196 + j*4]) = v;
        }
        __syncthreads();

        float a00=0,a01=0,a10=0,a11=0;
        {
            const float* q0p = &sQM[tyn*196];
            const float* q1p = &sQM[(tyn+16)*196];
            const float* k0p = &sK[txm*196];
            const float* k1p = &sK[(txm+16)*196];
            for (int k = 0; k < D; k += 4) {
                float4 qa = *reinterpret_cast<const float4*>(q0p+k);
                float4 qc = *reinterpret_cast<const float4*>(q1p+k);
                float4 ka = *reinterpret_cast<const float4*>(k0p+k);
                float4 kc = *reinterpret_cast<const float4*>(k1p+k);
                a00 += qa.x*ka.x + qa.y*ka.y + qa.z*ka.z + qa.w*ka.w;
                a01 += qa.x*kc.x + qa.y*kc.y + qa.z*kc.z + qa.w*kc.w;
                a10 += qc.x*ka.x + qc.y*ka.y + qc.z*ka.z + qc.w*ka.w;
                a11 += qc.x*kc.x + qc.y*kc.y + qc.z*kc.z + qc.w*kc.w;
            }
        }
        sS[tyn*33 + txm]          = a00;
        sS[tyn*33 + txm+16]       = a01;
        sS[(tyn+16)*33 + txm]     = a10;
        sS[(tyn+16)*33 + txm+16]  = a11;
        __syncthreads();

        const int srow = tid >> 3, sj = tid & 7;
        {
            const float* r = &sS[srow*33];
            float mx = fmaxf(fmaxf(r[sj], r[sj+8]), fmaxf(r[sj+16], r[sj+24]));
            sTmp[srow*8 + sj] = mx;
        }
        __syncthreads();
        if (tid < 32) {
            float mx = sTmp[tid*8];
            #pragma unroll
            for (int j = 1; j < 8; ++j) mx = fmaxf(mx, sTmp[tid*8+j]);
            float om = sMaxRun[tid];
            float nm = fmaxf(om, mx);
            sR[tid] = __expf(om - nm);
            sMaxRun[tid] = nm;
        }
        __syncthreads();
        {
            float nm = sMaxRun[srow];
            float* r = &sS[srow*33];
            float p0 = __expf(r[sj]    - nm);
            float p1 = __expf(r[sj+8]  - nm);
            float p2 = __expf(r[sj+16] - nm);
            float p3 = __expf(r[sj+24] - nm);
            r[sj] = p0; r[sj+8] = p1; r[sj+16] = p2; r[sj+24] = p3;
            sTmp[srow*8+sj] = p0+p1+p2+p3;
        }
        __syncthreads();
        if (tid < 32) {
            float s = 0.0f;
            #pragma unroll
            for (int j = 0; j < 8; ++j) s += sTmp[tid*8+j];
            sSumRun[tid] = sSumRun[tid]*sR[tid] + s;
        }
        {
            float r0 = sR[gn*4+0], r1 = sR[gn*4+1], r2 = sR[gn*4+2], r3 = sR[gn*4+3];
            #pragma unroll
            for (int b = 0; b < 6; ++b) { vacc[0][b]*=r0; vacc[1][b]*=r1; vacc[2][b]*=r2; vacc[3][b]*=r3; }
            for (int m = 0; m < 32; ++m) {
                float p0 = sS[(gn*4+0)*33+m];
                float p1 = sS[(gn*4+1)*33+m];
                float p2 = sS[(gn*4+2)*33+m];
                float p3 = sS[(gn*4+3)*33+m];
                const float* kr = &sK[m*196 + cbase];
                #pragma unroll
                for (int b = 0; b < 6; ++b) {
                    float kv = kr[b];
                    vacc[0][b] += p0*kv;
                    vacc[1][b] += p1*kv;
                    vacc[2][b] += p2*kv;
                    vacc[3][b] += p3*kv;
                }
            }
        }
    }

    __syncthreads();
    {
        float i0 = 1.0f/sSumRun[gn*4+0], i1 = 1.0f/sSumRun[gn*4+1];
        float i2 = 1.0f/sSumRun[gn*4+2], i3 = 1.0f/sSumRun[gn*4+3];
        #pragma unroll
        for (int b = 0; b < 6; ++b) {
            sQM[(gn*4+0)*196 + cbase + b] = vacc[0][b]*i0;
            sQM[(gn*4+1)*196 + cbase + b] = vacc[1][b]*i1;
            sQM[(gn*4+2)*196 + cbase + b] = vacc[2][b]*i2;
            sQM[(gn*4+3)*196 + cbase + b] = vacc[3][b]*i3;
        }
    }
    for (int i = tid; i < 32*D/4; i += 256)
        reinterpret_cast<float4*>(sK)[i] = reinterpret_cast<const float4*>(Ah)[i];
    __syncthreads();

    #pragma unroll
    for (int kk = 0; kk < 4; ++kk) {
        int p = tid + kk*256;
        int n = p >> 5, g = p & 31;
        float acc[6] = {0,0,0,0,0,0};
        const float* vb = &sQM[n*196];
        const float* ab = &sK[g*D];
        for (int f = 0; f < 32; ++f) {
            const float* vf = vb + f*6;
            const float* af = ab + f*6;
            #pragma unroll
            for (int z = 0; z < 3; ++z) {
                float V0 = vf[2*z], V1 = vf[2*z+1];
                float A0 = af[2*z], A1 = af[2*z+1];
                acc[2*z]   += A0*V0 - A1*V1;
                acc[2*z+1] += A0*V1 + A1*V0;
            }
        }
        float* op = ob + (size_t)(nt*32 + n)*D + g*6;
        #pragma unroll
        for (int j = 0; j < 6; ++j) atomicAdd(op + j, acc[j]);
    }
}

extern "C" void kernel_launch(void* const* d_in, const int* in_sizes, int n_in,
                              void* d_out, int out_size, void* d_ws, size_t ws_size,
                              hipStream_t stream) {
    const float* x   = (const float*)d_in[0];
    const float* Muu = (const float*)d_in[1];
    const float* Mdd = (const float*)d_in[2];
    const float* Mud = (const float*)d_in[3];
    const float* Mdu = (const float*)d_in[4];
    const float* Auu = (const float*)d_in[5];
    const float* Add = (const float*)d_in[6];
    const float* Aud = (const float*)d_in[7];
    const float* Adu = (const float*)d_in[8];
    float* outp = (float*)d_out;

    if (ws_size >= WS_NEED) {
        char* ws = (char*)d_ws;
        u16* xh  = (u16*)(ws + XH_OFF);
        u16* xl  = (u16*)(ws + XL_OFF);
        u16* xT  = (u16*)(ws + XT_OFF);
        u16* wtp = (u16*)(ws + WTP_OFF);
        u16* mth = (u16*)(ws + MTH_OFF);
        u16* mtl = (u16*)(ws + MTL_OFF);
        u16* qmh = (u16*)(ws + QMH_OFF);
        u16* qml = (u16*)(ws + QML_OFF);
        u16* y   = (u16*)(ws + Y_OFF);

        prep_x<<<768, 512, 0, stream>>>(x, xh, xl, xT);
        prep_wm<<<4608, 512, 0, stream>>>(Muu, Mdd, Mud, Mdu,
                                          Auu, Add, Aud, Adu, wtp, mth, mtl);
        prep_qmf2<<<dim3(8, 16, 4), 256, 0, stream>>>(xh, xl, mth, mtl, qmh, qml);
        attn_mfma<<<dim3(4, 16, 4), 512, 0, stream>>>(qmh, qml, xh, xT, wtp, y);
        reduce_y<<<96, 512, 0, stream>>>(y, outp);
    } else {
        (void)hipMemsetAsync(d_out, 0, (size_t)out_size * sizeof(float), stream);
        attn_fused_fb<<<dim3(32, 16, 4), 256, 0, stream>>>(x, Muu, Mdd, Mud, Mdu,
                                                           Auu, Add, Aud, Adu, outp);
    }
}

// Round 11
// 151.871 us; speedup vs baseline: 3.0356x; 1.1526x over previous
//
#include <hip/hip_runtime.h>
#include <hip/hip_bf16.h>

typedef unsigned short u16;
typedef unsigned int   u32;
typedef _Float16 f16x8 __attribute__((ext_vector_type(8)));
typedef float    f32x16 __attribute__((ext_vector_type(16)));

#define HEADS 16
#define D     192
#define NUP   1024

// ---- workspace layout (bytes) ----
#define XB       (2048ull*192*2)               // 786432
#define XH_OFF   0ull
#define XL_OFF   (XH_OFF + XB)
#define XT_OFF   (XL_OFF + XB)
#define WM_BYTES (64ull*192*192*2)             // 4718592
#define WTP_OFF  (XT_OFF + XB)
#define MTH_OFF  (WTP_OFF + WM_BYTES)
#define MTL_OFF  (MTH_OFF + WM_BYTES)
#define QM_BYTES (64ull*1024*192*2)            // 25165824 (fp16)
#define QMH_OFF  (MTH_OFF + 2*WM_BYTES)
#define Y_OFF    (QMH_OFF + QM_BYTES)
#define WS_NEED  (Y_OFF + QM_BYTES)            // 66846720

__device__ __forceinline__ u16 f2h(float v) {
    _Float16 h = (_Float16)v;
    return __builtin_bit_cast(u16, h);
}
__device__ __forceinline__ float h2f(u16 v) {
    return (float)__builtin_bit_cast(_Float16, v);
}
__device__ __forceinline__ u32 pk2h(float a, float b) {      // RNE (prep path)
    return (u32)f2h(a) | ((u32)f2h(b) << 16);
}
__device__ __forceinline__ u32 pk2h_rtz(float a, float b) {  // 1-instr packed
    auto r = __builtin_amdgcn_cvt_pkrtz(a, b);
    return __builtin_bit_cast(u32, r);
}

// =====================================================================
// helper: assemble B-fragment (32x32x16) from 4 packed-pair u32s in
// D-frag order (m = (r&3)+8*(r>>2)+4*(lane>>5)) via half-swap (shfl —
// HW-verified in R2..R8; permlane variant produced NaN in R10)
// =====================================================================
__device__ __forceinline__ f16x8 make_bfrag(u32 q0, u32 q1, u32 q2, u32 q3, bool hi) {
    u32 s0 = (u32)__shfl_xor((int)q0, 32);
    u32 s1 = (u32)__shfl_xor((int)q1, 32);
    u32 s2 = (u32)__shfl_xor((int)q2, 32);
    u32 s3 = (u32)__shfl_xor((int)q3, 32);
    uint4 w;
    w.x = hi ? s2 : q0;  w.y = hi ? s3 : q1;
    w.z = hi ? q2 : s0;  w.w = hi ? q3 : s1;
    return __builtin_bit_cast(f16x8, w);
}

// =====================================================================
// Prep ALL (merged): blocks [0,768) do x->xh,xl,xT ; rest build WT/MT.
// =====================================================================
__global__ __launch_bounds__(512)
void prep_all(const float* __restrict__ x,
              const float* __restrict__ Muu, const float* __restrict__ Mdd,
              const float* __restrict__ Mud, const float* __restrict__ Mdu,
              const float* __restrict__ Auu, const float* __restrict__ Add,
              const float* __restrict__ Aud, const float* __restrict__ Adu,
              u16* __restrict__ xh, u16* __restrict__ xl, u16* __restrict__ xT,
              u16* __restrict__ wtp, u16* __restrict__ mth, u16* __restrict__ mtl)
{
    int b = blockIdx.x;
    if (b < 768) {
        int i = b*512 + threadIdx.x;           // < 2048*192
        float v = x[i];
        int n = i / D, d = i - n*D;
        u16 hi = f2h(v);
        xh[i] = hi;
        xl[i] = f2h(v - h2f(hi));
        xT[(size_t)(n >> 5)*6144 + d*32 + (n & 31)] = hi;
        return;
    }
    int idx = (b - 768)*512 + threadIdx.x;     // < 64*36864
    int th = idx / 36864, r = idx - th*36864;
    int dout = r / 192, din = r - dout*192;
    int t = th >> 4, h = th & 15;
    const float* Ap = (t==0)?Auu:(t==1)?Aud:(t==2)?Add:Adu;
    const float* Mp = (t==0)?Muu:(t==1)?Mud:(t==2)?Mdd:Mdu;
    int g = dout / 6, zc = dout - g*6, z = zc >> 1, b0 = zc & 1;
    int f = din / 6,  zb = din - f*6,  z2 = zb >> 1, b1 = zb & 1;

    float wv = 0.0f, mv = 0.0f;
    if (z2 == z) {
        const float* a = Ap + (((size_t)h*32 + g)*32 + f)*6 + z*2;
        float A0 = a[0], A1 = a[1];
        wv = (b0 == 0) ? (b1 == 0 ? A0 : -A1) : (b1 == 0 ? A1 : A0);
        const float* m = Mp + (((size_t)h*32 + f)*32 + g)*6 + z*2;
        float M0 = m[0], M1 = m[1];
        mv = (b0 == 0) ? (b1 == 0 ? M0 : -M1) : (b1 == 0 ? M1 : M0);
    }
    int ob = dout >> 5, l31 = dout & 31;
    int ks = din >> 4, kr = din & 15, g32 = kr >> 3, j = kr & 7;
    size_t pidx = ((((size_t)th*6 + ob)*12 + ks)*64 + g32*32 + l31)*8 + j;
    wtp[pidx] = f2h(wv);
    u16 mh = f2h(mv);
    mth[pidx] = mh;
    mtl[pidx] = f2h(mv - h2f(mh));
}

// =====================================================================
// Prep C: QM via MFMA (3-term fp16 split), row layout qm[th][n][192] fp16
// (hi only — 1-term scores). D-frag: col=l31, row=(r&3)+8*(r>>2)+4*g32.
// =====================================================================
__global__ __launch_bounds__(256, 2)
void prep_qmf2(const u16* __restrict__ xh_g, const u16* __restrict__ xl_g,
               const u16* __restrict__ mth_g, const u16* __restrict__ mtl_g,
               u16* __restrict__ qmh)
{
    const int nt = blockIdx.x, h = blockIdx.y, t = blockIdx.z;
    const int tid  = threadIdx.x;
    const int lane = tid & 63;
    const int l31  = lane & 31;
    const int g32  = lane >> 5;
    const int wave = tid >> 6;
    const int th   = t*16 + h;
    const int ntile = nt*4 + wave;
    const int n0   = ntile*32;
    const int qoff = (t <= 1) ? 0 : NUP;

    f16x8 bxh[12], bxl[12];
    const u16* xrh = xh_g + (size_t)(qoff + n0 + l31)*D;
    const u16* xrl = xl_g + (size_t)(qoff + n0 + l31)*D;
    #pragma unroll
    for (int ks = 0; ks < 12; ++ks) {
        bxh[ks] = *reinterpret_cast<const f16x8*>(xrh + ks*16 + g32*8);
        bxl[ks] = *reinterpret_cast<const f16x8*>(xrl + ks*16 + g32*8);
    }
    const u16* mthb = mth_g + (size_t)th*36864;
    const u16* mtlb = mtl_g + (size_t)th*36864;
    u16* dhrow = qmh + ((size_t)th*1024 + n0 + l31)*D + 4*g32;

    #pragma unroll
    for (int ob = 0; ob < 6; ++ob) {
        f32x16 a;
        #pragma unroll
        for (int i = 0; i < 16; ++i) a[i] = 0.0f;
        #pragma unroll
        for (int ks = 0; ks < 12; ++ks) {
            size_t fo = (((size_t)ob*12 + ks)*64 + lane)*8;
            f16x8 amh = *reinterpret_cast<const f16x8*>(mthb + fo);
            f16x8 aml = *reinterpret_cast<const f16x8*>(mtlb + fo);
            a = __builtin_amdgcn_mfma_f32_32x32x16_f16(amh, bxh[ks], a, 0, 0, 0);
            a = __builtin_amdgcn_mfma_f32_32x32x16_f16(amh, bxl[ks], a, 0, 0, 0);
            a = __builtin_amdgcn_mfma_f32_32x32x16_f16(aml, bxh[ks], a, 0, 0, 0);
        }
        #pragma unroll
        for (int q2 = 0; q2 < 4; ++q2) {
            uint2 wh;
            wh.x = pk2h(a[q2*4+0], a[q2*4+1]);
            wh.y = pk2h(a[q2*4+2], a[q2*4+3]);
            *reinterpret_cast<uint2*>(dhrow + ob*32 + q2*8) = wh;
        }
    }
}

// =====================================================================
// Main fused kernel — 8 waves x 32 q-rows, 512 threads, grid (4,16,4).
// 1-term fp16 scores (12 MFMA) + PV (12 MFMA). T15 lag-softmax pipeline:
// scores(t) issue while softmax(t-1) runs on VALU, then PV(t-1).
// Triple-buffered LDS, one barrier/iter. Shfl-based cross-half ops.
// =====================================================================
__global__ __launch_bounds__(512, 2)
void attn_mfma(const u16* __restrict__ qmh_g, const u16* __restrict__ xh_g,
               const u16* __restrict__ xT_g,  const u16* __restrict__ wtp_g,
               u16* __restrict__ y_g)
{
    const int nt = blockIdx.x, h = blockIdx.y, t = blockIdx.z;
    const int tid  = threadIdx.x;
    const int lane = tid & 63;
    const int l31  = lane & 31;
    const int g32  = lane >> 5;
    const int th   = t*16 + h;
    const int n0   = nt*256 + (tid >> 6)*32;
    const int koff = (t == 1 || t == 2) ? NUP : 0;   // k/v-side rows
    const int mtb  = koff >> 5;

    __shared__ u16 sXh[3][32*200];
    __shared__ u16 sXT[3][192*40];

    // --- QM fragments (B operand), resident ---
    f16x8 qh[12];
    {
        const u16* bh = qmh_g + ((size_t)th*1024 + n0 + l31)*D;
        #pragma unroll
        for (int ks = 0; ks < 12; ++ks)
            qh[ks] = *reinterpret_cast<const f16x8*>(bh + ks*16 + g32*8);
    }

    f32x16 vt[6];
    #pragma unroll
    for (int ob = 0; ob < 6; ++ob)
        #pragma unroll
        for (int i = 0; i < 16; ++i) vt[ob][i] = 0.0f;

    float run_m = -3.0e38f, run_l = 0.0f;

    uint4 ld[3];
    auto load_tile = [&](int mt) {
        const int krow0 = koff + mt*32;
        #pragma unroll
        for (int i = 0; i < 3; ++i) {
            int c = tid + i*512;
            const u16* gp;
            if (c < 768) {
                int rr = c/24, cc = c - rr*24;
                gp = xh_g + (size_t)(krow0 + rr)*D + cc*8;
            } else {
                int c3 = c - 768, dd = c3 >> 2, qq = c3 & 3;
                gp = xT_g + (size_t)(mtb + mt)*6144 + dd*32 + qq*8;
            }
            ld[i] = *reinterpret_cast<const uint4*>(gp);
        }
    };
    auto store_tile = [&](int buf) {
        #pragma unroll
        for (int i = 0; i < 3; ++i) {
            int c = tid + i*512;
            u16* lp;
            if (c < 768) {
                int rr = c/24, cc = c - rr*24;  lp = &sXh[buf][rr*200 + cc*8];
            } else {
                int c3 = c - 768, dd = c3 >> 2, qq = c3 & 3;  lp = &sXT[buf][dd*40 + qq*8];
            }
            *reinterpret_cast<uint4*>(lp) = ld[i];
        }
    };
    auto SCORES = [&](int bc, f32x16 &sOut) {
        #pragma unroll
        for (int i = 0; i < 16; ++i) sOut[i] = 0.0f;
        __builtin_amdgcn_s_setprio(1);
        #pragma unroll
        for (int ks = 0; ks < 12; ++ks) {
            f16x8 ah = *reinterpret_cast<const f16x8*>(&sXh[bc][l31*200 + ks*16 + g32*8]);
            sOut = __builtin_amdgcn_mfma_f32_32x32x16_f16(ah, qh[ks], sOut, 0, 0, 0);
        }
        __builtin_amdgcn_s_setprio(0);
    };
    auto SOFTMAX = [&](f32x16 &sIn, f16x8 &pf0, f16x8 &pf1) {
        float tmax = sIn[0];
        #pragma unroll
        for (int i = 1; i < 16; ++i) tmax = fmaxf(tmax, sIn[i]);
        tmax = fmaxf(tmax, __shfl_xor(tmax, 32));
        if (__any(tmax > run_m + 8.0f)) {       // defer-rescale (T13)
            float nm = fmaxf(run_m, tmax);
            float rs = __expf(run_m - nm);
            #pragma unroll
            for (int ob = 0; ob < 6; ++ob)
                #pragma unroll
                for (int i = 0; i < 16; ++i) vt[ob][i] *= rs;
            run_l *= rs;
            run_m = nm;
        }
        float psum = 0.0f;
        u32 q[8];
        #pragma unroll
        for (int j = 0; j < 8; ++j) {
            float p0 = __expf(sIn[2*j]   - run_m);
            float p1 = __expf(sIn[2*j+1] - run_m);
            psum += p0 + p1;
            q[j] = pk2h_rtz(p0, p1);
        }
        psum += __shfl_xor(psum, 32);
        run_l += psum;
        pf0 = make_bfrag(q[0], q[1], q[2], q[3], g32);
        pf1 = make_bfrag(q[4], q[5], q[6], q[7], g32);
    };
    auto PV = [&](int bp, f16x8 pf0, f16x8 pf1) {
        __builtin_amdgcn_s_setprio(1);
        #pragma unroll
        for (int ob = 0; ob < 6; ++ob) {
            f16x8 a0 = *reinterpret_cast<const f16x8*>(&sXT[bp][(ob*32 + l31)*40 + g32*8]);
            f16x8 a1 = *reinterpret_cast<const f16x8*>(&sXT[bp][(ob*32 + l31)*40 + 16 + g32*8]);
            vt[ob] = __builtin_amdgcn_mfma_f32_32x32x16_f16(a0, pf0, vt[ob], 0, 0, 0);
            vt[ob] = __builtin_amdgcn_mfma_f32_32x32x16_f16(a1, pf1, vt[ob], 0, 0, 0);
        }
        __builtin_amdgcn_s_setprio(0);
    };

    f32x16 sA, sB;

    // ---- prologue: tile0 staged+scored; tile1 staged ----
    load_tile(0); store_tile(0); __syncthreads();
    load_tile(1);
    SCORES(0, sA);
    store_tile(1); __syncthreads();

    auto STEP = [&](int cur, f32x16 &sCur, f32x16 &sPrev, int bC, int bP, int bN) {
        if (cur < 31) load_tile(cur + 1);
        SCORES(bC, sCur);                    // MFMA(cur) issues...
        f16x8 pf0, pf1;
        SOFTMAX(sPrev, pf0, pf1);            // ...while VALU does softmax(prev)
        PV(bP, pf0, pf1);
        if (cur < 31) store_tile(bN);
        __syncthreads();
    };

    // buffers at cur=1: cur%3=1, prev=0, next=2; rotate each step
    int b0 = 1, b1 = 0, b2 = 2;
    #pragma unroll 1
    for (int m2 = 1; m2 <= 29; m2 += 2) {
        STEP(m2,     sB, sA, b0, b1, b2);
        { int tq = b1; b1 = b0; b0 = b2; b2 = tq; }
        STEP(m2 + 1, sA, sB, b0, b1, b2);
        { int tq = b1; b1 = b0; b0 = b2; b2 = tq; }
    }
    STEP(31, sB, sA, b0, b1, b2);            // scores(31), softmax+PV(30)
    // ---- epilogue: softmax + PV of tile31 (lives in buffer b0) ----
    {
        f16x8 pf0, pf1;
        SOFTMAX(sB, pf0, pf1);
        PV(b0, pf0, pf1);
    }

    // --- normalize ---
    float inv = 1.0f / run_l;
    #pragma unroll
    for (int ob = 0; ob < 6; ++ob)
        #pragma unroll
        for (int i = 0; i < 16; ++i) vt[ob][i] *= inv;

    // --- combine: Y^T[dout][n] = sum_din WT[dout][din] * Vt^T[din][n] ---
    const u16* wbase = wtp_g + (size_t)th*36864;
    f32x16 y[6];
    #pragma unroll
    for (int ob = 0; ob < 6; ++ob)
        #pragma unroll
        for (int i = 0; i < 16; ++i) y[ob][i] = 0.0f;

    #pragma unroll
    for (int ob = 0; ob < 6; ++ob) {
        u32 qq[8];
        #pragma unroll
        for (int j = 0; j < 8; ++j) qq[j] = pk2h_rtz(vt[ob][2*j], vt[ob][2*j+1]);
        #pragma unroll
        for (int half = 0; half < 2; ++half) {
            int ks = ob*2 + half;
            f16x8 bfr = half ? make_bfrag(qq[4], qq[5], qq[6], qq[7], g32)
                             : make_bfrag(qq[0], qq[1], qq[2], qq[3], g32);
            #pragma unroll
            for (int ob2 = 0; ob2 < 6; ++ob2) {
                f16x8 a = *reinterpret_cast<const f16x8*>(
                    wbase + ((((size_t)ob2*12) + ks)*64 + lane)*8);
                y[ob2] = __builtin_amdgcn_mfma_f32_32x32x16_f16(a, bfr, y[ob2], 0, 0, 0);
            }
        }
    }

    // --- write partial Y[t][h][n][dout] (fp16) ---
    u16* yrow = y_g + ((size_t)th*1024 + n0 + l31)*D;
    #pragma unroll
    for (int ob = 0; ob < 6; ++ob)
        #pragma unroll
        for (int rq = 0; rq < 4; ++rq) {
            uint2 v;
            v.x = pk2h_rtz(y[ob][rq*4+0], y[ob][rq*4+1]);
            v.y = pk2h_rtz(y[ob][rq*4+2], y[ob][rq*4+3]);
            *reinterpret_cast<uint2*>(yrow + ob*32 + rq*8 + g32*4) = v;
        }
}

// =====================================================================
// Reduce: out[p*1024+n][d] = sum_{t in pair, h} y[t][h][n][d]  (fp16 in)
// =====================================================================
__global__ __launch_bounds__(512)
void reduce_y(const u16* __restrict__ y_g, float* __restrict__ out)
{
    int gi = blockIdx.x*512 + threadIdx.x;     // < 2048*192/8
    int n = gi / 24, c = gi - n*24;
    int p = n >> 10, nn = n & 1023;
    float acc[8];
    #pragma unroll
    for (int j = 0; j < 8; ++j) acc[j] = 0.0f;
    #pragma unroll
    for (int k = 0; k < 32; ++k) {
        int tcur = p*2 + (k >> 4), hh = k & 15;
        uint4 v = *reinterpret_cast<const uint4*>(
            y_g + ((size_t)((tcur*16+hh)*1024 + nn))*D + c*8);
        u32 w[4] = {v.x, v.y, v.z, v.w};
        #pragma unroll
        for (int j = 0; j < 4; ++j) {
            acc[2*j]   += h2f((u16)(w[j] & 0xffffu));
            acc[2*j+1] += h2f((u16)(w[j] >> 16));
        }
    }
    float* op = out + (size_t)n*D + c*8;
    float4 o0 = {acc[0], acc[1], acc[2], acc[3]};
    float4 o1 = {acc[4], acc[5], acc[6], acc[7]};
    *reinterpret_cast<float4*>(op)     = o0;
    *reinterpret_cast<float4*>(op + 4) = o1;
}

// =====================================================================
// Fallback (round-1 fp32 kernel) if ws too small
// =====================================================================
__global__ __launch_bounds__(256, 2)
void attn_fused_fb(const float* __restrict__ x,
                const float* __restrict__ Muu, const float* __restrict__ Mdd,
                const float* __restrict__ Mud, const float* __restrict__ Mdu,
                const float* __restrict__ Auu, const float* __restrict__ Add,
                const float* __restrict__ Aud, const float* __restrict__ Adu,
                float* __restrict__ out)
{
    const int nt  = blockIdx.x;
    const int h   = blockIdx.y;
    const int t   = blockIdx.z;
    const int tid = threadIdx.x;
    const float* qb = (t <= 1) ? x : x + (size_t)NUP*D;
    const float* kb = (t == 0 || t == 3) ? x : x + (size_t)NUP*D;
    const float* Mp = (t==0)?Muu:(t==1)?Mud:(t==2)?Mdd:Mdu;
    const float* Ap = (t==0)?Auu:(t==1)?Aud:(t==2)?Add:Adu;
    const float* Mh = Mp + (size_t)h*32*D;
    const float* Ah = Ap + (size_t)h*32*D;
    float* ob = out + ((t>=2) ? (size_t)NUP*D : 0);

    __shared__ float sK[32*196];
    __shared__ float sQM[32*196];
    __shared__ float sS[32*33];
    __shared__ float sTmp[32*8];
    __shared__ float sR[32];
    __shared__ float sMaxRun[32];
    __shared__ float sSumRun[32];

    if (tid < 32) { sMaxRun[tid] = -3.0e38f; sSumRun[tid] = 0.0f; }
    for (int i = tid; i < 32*D/4; i += 256)
        reinterpret_cast<float4*>(sK)[i] = reinterpret_cast<const float4*>(Mh)[i];
    __syncthreads();

    #pragma unroll
    for (int kk = 0; kk < 4; ++kk) {
        int p = tid + kk*256;
        int n = p >> 5, g = p & 31;
        const float* qrow = qb + (size_t)(nt*32 + n)*D;
        float acc[6] = {0,0,0,0,0,0};
        for (int f = 0; f < 32; ++f) {
            const float* qf = qrow + f*6;
            const float* mf = sK + f*D + g*6;
            #pragma unroll
            for (int z = 0; z < 3; ++z) {
                float q0 = qf[2*z], q1 = qf[2*z+1];
                float m0 = mf[2*z], m1 = mf[2*z+1];
                acc[2*z]   += q0*m0 - q1*m1;
                acc[2*z+1] += q1*m0 + q0*m1;
            }
        }
        #pragma unroll
        for (int j = 0; j < 6; ++j) sQM[n*196 + g*6 + j] = acc[j];
    }

    const int gn = tid >> 5;
    const int cg = tid & 31;
    const int cbase = cg*6;
    float vacc[4][6];
    #pragma unroll
    for (int a = 0; a < 4; ++a)
        #pragma unroll
        for (int b = 0; b < 6; ++b) vacc[a][b] = 0.0f;

    const int txm = tid & 15, tyn = tid >> 4;

    for (int mt = 0; mt < 32; ++mt) {
        __syncthreads();
        for (int i = tid; i < 32*(D/4); i += 256) {
            int row = i / (D/4), j = i - row*(D/4);
            float4 v = reinterpret_cast<const float4*>(kb + (size_t)(mt*32 + row)*D)[j];
            *reinterpret_cast<float4*>(&sK[row*196 + j*4]) = v;
        }
        __syncthreads();

        float a00=0,a01=0,a10=0,a11=0;
        {
            const float* q0p = &sQM[tyn*196];
            const float* q1p = &sQM[(tyn+16)*196];
            const float* k0p = &sK[txm*196];
            const float* k1p = &sK[(txm+16)*196];
            for (int k = 0; k < D; k += 4) {
                float4 qa = *reinterpret_cast<const float4*>(q0p+k);
                float4 qc = *reinterpret_cast<const float4*>(q1p+k);
                float4 ka = *reinterpret_cast<const float4*>(k0p+k);
                float4 kc = *reinterpret_cast<const float4*>(k1p+k);
                a00 += qa.x*ka.x + qa.y*ka.y + qa.z*ka.z + qa.w*ka.w;
                a01 += qa.x*kc.x + qa.y*kc.y + qa.z*kc.z + qa.w*kc.w;
                a10 += qc.x*ka.x + qc.y*ka.y + qc.z*ka.z + qc.w*ka.w;
                a11 += qc.x*kc.x + qc.y*kc.y + qc.z*kc.z + qc.w*kc.w;
            }
        }
        sS[tyn*33 + txm]          = a00;
        sS[tyn*33 + txm+16]       = a01;
        sS[(tyn+16)*33 + txm]     = a10;
        sS[(tyn+16)*33 + txm+16]  = a11;
        __syncthreads();

        const int srow = tid >> 3, sj = tid & 7;
        {
            const float* r = &sS[srow*33];
            float mx = fmaxf(fmaxf(r[sj], r[sj+8]), fmaxf(r[sj+16], r[sj+24]));
            sTmp[srow*8 + sj] = mx;
        }
        __syncthreads();
        if (tid < 32) {
            float mx = sTmp[tid*8];
            #pragma unroll
            for (int j = 1; j < 8; ++j) mx = fmaxf(mx, sTmp[tid*8+j]);
            float om = sMaxRun[tid];
            float nm = fmaxf(om, mx);
            sR[tid] = __expf(om - nm);
            sMaxRun[tid] = nm;
        }
        __syncthreads();
        {
            float nm = sMaxRun[srow];
            float* r = &sS[srow*33];
            float p0 = __expf(r[sj]    - nm);
            float p1 = __expf(r[sj+8]  - nm);
            float p2 = __expf(r[sj+16] - nm);
            float p3 = __expf(r[sj+24] - nm);
            r[sj] = p0; r[sj+8] = p1; r[sj+16] = p2; r[sj+24] = p3;
            sTmp[srow*8+sj] = p0+p1+p2+p3;
        }
        __syncthreads();
        if (tid < 32) {
            float s = 0.0f;
            #pragma unroll
            for (int j = 0; j < 8; ++j) s += sTmp[tid*8+j];
            sSumRun[tid] = sSumRun[tid]*sR[tid] + s;
        }
        {
            float r0 = sR[gn*4+0], r1 = sR[gn*4+1], r2 = sR[gn*4+2], r3 = sR[gn*4+3];
            #pragma unroll
            for (int b = 0; b < 6; ++b) { vacc[0][b]*=r0; vacc[1][b]*=r1; vacc[2][b]*=r2; vacc[3][b]*=r3; }
            for (int m = 0; m < 32; ++m) {
                float p0 = sS[(gn*4+0)*33+m];
                float p1 = sS[(gn*4+1)*33+m];
                float p2 = sS[(gn*4+2)*33+m];
                float p3 = sS[(gn*4+3)*33+m];
                const float* kr = &sK[m*196 + cbase];
                #pragma unroll
                for (int b = 0; b < 6; ++b) {
                    float kv = kr[b];
                    vacc[0][b] += p0*kv;
                    vacc[1][b] += p1*kv;
                    vacc[2][b] += p2*kv;
                    vacc[3][b] += p3*kv;
                }
            }
        }
    }

    __syncthreads();
    {
        float i0 = 1.0f/sSumRun[gn*4+0], i1 = 1.0f/sSumRun[gn*4+1];
        float i2 = 1.0f/sSumRun[gn*4+2], i3 = 1.0f/sSumRun[gn*4+3];
        #pragma unroll
        for (int b = 0; b < 6; ++b) {
            sQM[(gn*4+0)*196 + cbase + b] = vacc[0][b]*i0;
            sQM[(gn*4+1)*196 + cbase + b] = vacc[1][b]*i1;
            sQM[(gn*4+2)*196 + cbase + b] = vacc[2][b]*i2;
            sQM[(gn*4+3)*196 + cbase + b] = vacc[3][b]*i3;
        }
    }
    for (int i = tid; i < 32*D/4; i += 256)
        reinterpret_cast<float4*>(sK)[i] = reinterpret_cast<const float4*>(Ah)[i];
    __syncthreads();

    #pragma unroll
    for (int kk = 0; kk < 4; ++kk) {
        int p = tid + kk*256;
        int n = p >> 5, g = p & 31;
        float acc[6] = {0,0,0,0,0,0};
        const float* vb = &sQM[n*196];
        const float* ab = &sK[g*D];
        for (int f = 0; f < 32; ++f) {
            const float* vf = vb + f*6;
            const float* af = ab + f*6;
            #pragma unroll
            for (int z = 0; z < 3; ++z) {
                float V0 = vf[2*z], V1 = vf[2*z+1];
                float A0 = af[2*z], A1 = af[2*z+1];
                acc[2*z]   += A0*V0 - A1*V1;
                acc[2*z+1] += A0*V1 + A1*V0;
            }
        }
        float* op = ob + (size_t)(nt*32 + n)*D + g*6;
        #pragma unroll
        for (int j = 0; j < 6; ++j) atomicAdd(op + j, acc[j]);
    }
}

extern "C" void kernel_launch(void* const* d_in, const int* in_sizes, int n_in,
                              void* d_out, int out_size, void* d_ws, size_t ws_size,
                              hipStream_t stream) {
    const float* x   = (const float*)d_in[0];
    const float* Muu = (const float*)d_in[1];
    const float* Mdd = (const float*)d_in[2];
    const float* Mud = (const float*)d_in[3];
    const float* Mdu = (const float*)d_in[4];
    const float* Auu = (const float*)d_in[5];
    const float* Add = (const float*)d_in[6];
    const float* Aud = (const float*)d_in[7];
    const float* Adu = (const float*)d_in[8];
    float* outp = (float*)d_out;

    if (ws_size >= WS_NEED) {
        char* ws = (char*)d_ws;
        u16* xh  = (u16*)(ws + XH_OFF);
        u16* xl  = (u16*)(ws + XL_OFF);
        u16* xT  = (u16*)(ws + XT_OFF);
        u16* wtp = (u16*)(ws + WTP_OFF);
        u16* mth = (u16*)(ws + MTH_OFF);
        u16* mtl = (u16*)(ws + MTL_OFF);
        u16* qmh = (u16*)(ws + QMH_OFF);
        u16* y   = (u16*)(ws + Y_OFF);

        prep_all<<<5376, 512, 0, stream>>>(x, Muu, Mdd, Mud, Mdu,
                                           Auu, Add, Aud, Adu,
                                           xh, xl, xT, wtp, mth, mtl);
        prep_qmf2<<<dim3(8, 16, 4), 256, 0, stream>>>(xh, xl, mth, mtl, qmh);
        attn_mfma<<<dim3(4, 16, 4), 512, 0, stream>>>(qmh, xh, xT, wtp, y);
        reduce_y<<<96, 512, 0, stream>>>(y, outp);
    } else {
        (void)hipMemsetAsync(d_out, 0, (size_t)out_size * sizeof(float), stream);
        attn_fused_fb<<<dim3(32, 16, 4), 256, 0, stream>>>(x, Muu, Mdd, Mud, Mdu,
                                                           Auu, Add, Aud, Adu, outp);
    }
}

// Round 12
// 128.418 us; speedup vs baseline: 3.5900x; 1.1826x over previous
//
#include <hip/hip_runtime.h>
#include <hip/hip_bf16.h>

typedef unsigned short u16;
typedef unsigned int   u32;
typedef _Float16 f16x8 __attribute__((ext_vector_type(8)));
typedef float    f32x16 __attribute__((ext_vector_type(16)));

#define HEADS 16
#define D     192
#define NUP   1024

// ---- workspace layout (bytes) ----
#define XB       (2048ull*192*2)               // 786432
#define XH_OFF   0ull
#define XL_OFF   (XH_OFF + XB)
#define XT_OFF   (XL_OFF + XB)
#define WM_BYTES (64ull*192*192*2)             // 4718592
#define WTP_OFF  (XT_OFF + XB)
#define MTH_OFF  (WTP_OFF + WM_BYTES)
#define MTL_OFF  (MTH_OFF + WM_BYTES)
#define Y_BYTES  (64ull*1024*192*2)            // 25165824 (fp16)
#define Y_OFF    (MTH_OFF + 2*WM_BYTES)
#define WS_NEED  (Y_OFF + Y_BYTES)             // 41680896

__device__ __forceinline__ u16 f2h(float v) {
    _Float16 h = (_Float16)v;
    return __builtin_bit_cast(u16, h);
}
__device__ __forceinline__ float h2f(u16 v) {
    return (float)__builtin_bit_cast(_Float16, v);
}
__device__ __forceinline__ u32 pk2h(float a, float b) {      // RNE
    return (u32)f2h(a) | ((u32)f2h(b) << 16);
}
__device__ __forceinline__ u32 pk2h_rtz(float a, float b) {  // 1-instr packed
    auto r = __builtin_amdgcn_cvt_pkrtz(a, b);
    return __builtin_bit_cast(u32, r);
}

// =====================================================================
// helper: assemble B-fragment (32x32x16) from 4 packed-pair u32s in
// D-frag order (m = (r&3)+8*(r>>2)+4*(lane>>5)) via half-swap (shfl —
// HW-verified R2..R11)
// =====================================================================
__device__ __forceinline__ f16x8 make_bfrag(u32 q0, u32 q1, u32 q2, u32 q3, bool hi) {
    u32 s0 = (u32)__shfl_xor((int)q0, 32);
    u32 s1 = (u32)__shfl_xor((int)q1, 32);
    u32 s2 = (u32)__shfl_xor((int)q2, 32);
    u32 s3 = (u32)__shfl_xor((int)q3, 32);
    uint4 w;
    w.x = hi ? s2 : q0;  w.y = hi ? s3 : q1;
    w.z = hi ? q2 : s0;  w.w = hi ? q3 : s1;
    return __builtin_bit_cast(f16x8, w);
}

// =====================================================================
// Prep ALL (merged): blocks [0,768) do x->xh,xl,xT ; rest build WT/MT.
// =====================================================================
__global__ __launch_bounds__(512)
void prep_all(const float* __restrict__ x,
              const float* __restrict__ Muu, const float* __restrict__ Mdd,
              const float* __restrict__ Mud, const float* __restrict__ Mdu,
              const float* __restrict__ Auu, const float* __restrict__ Add,
              const float* __restrict__ Aud, const float* __restrict__ Adu,
              u16* __restrict__ xh, u16* __restrict__ xl, u16* __restrict__ xT,
              u16* __restrict__ wtp, u16* __restrict__ mth, u16* __restrict__ mtl)
{
    int b = blockIdx.x;
    if (b < 768) {
        int i = b*512 + threadIdx.x;           // < 2048*192
        float v = x[i];
        int n = i / D, d = i - n*D;
        u16 hi = f2h(v);
        xh[i] = hi;
        xl[i] = f2h(v - h2f(hi));
        xT[(size_t)(n >> 5)*6144 + d*32 + (n & 31)] = hi;
        return;
    }
    int idx = (b - 768)*512 + threadIdx.x;     // < 64*36864
    int th = idx / 36864, r = idx - th*36864;
    int dout = r / 192, din = r - dout*192;
    int t = th >> 4, h = th & 15;
    const float* Ap = (t==0)?Auu:(t==1)?Aud:(t==2)?Add:Adu;
    const float* Mp = (t==0)?Muu:(t==1)?Mud:(t==2)?Mdd:Mdu;
    int g = dout / 6, zc = dout - g*6, z = zc >> 1, b0 = zc & 1;
    int f = din / 6,  zb = din - f*6,  z2 = zb >> 1, b1 = zb & 1;

    float wv = 0.0f, mv = 0.0f;
    if (z2 == z) {
        const float* a = Ap + (((size_t)h*32 + g)*32 + f)*6 + z*2;
        float A0 = a[0], A1 = a[1];
        wv = (b0 == 0) ? (b1 == 0 ? A0 : -A1) : (b1 == 0 ? A1 : A0);
        const float* m = Mp + (((size_t)h*32 + f)*32 + g)*6 + z*2;
        float M0 = m[0], M1 = m[1];
        mv = (b0 == 0) ? (b1 == 0 ? M0 : -M1) : (b1 == 0 ? M1 : M0);
    }
    int ob = dout >> 5, l31 = dout & 31;
    int ks = din >> 4, kr = din & 15, g32 = kr >> 3, j = kr & 7;
    size_t pidx = ((((size_t)th*6 + ob)*12 + ks)*64 + g32*32 + l31)*8 + j;
    wtp[pidx] = f2h(wv);
    u16 mh = f2h(mv);
    mth[pidx] = mh;
    mtl[pidx] = f2h(mv - h2f(mh));
}

// =====================================================================
// Main fused kernel — 8 waves x 32 q-rows, 512 threads, grid (4,16,4).
// Prologue: QM B-fragments via MFMA (3-term, 2-ob pairs) — merged from
// the old prep_qmf2 (R2/R4-verified make_bfrag path), no global round
// trip. K-loop: 1-term fp16 scores (2x6-chain split) + PV, T15 lag-
// softmax, triple-buffer LDS, one barrier/iter.
// =====================================================================
__global__ __launch_bounds__(512, 2)
void attn_mfma(const u16* __restrict__ xh_g,  const u16* __restrict__ xl_g,
               const u16* __restrict__ xT_g,  const u16* __restrict__ wtp_g,
               const u16* __restrict__ mth_g, const u16* __restrict__ mtl_g,
               u16* __restrict__ y_g)
{
    const int nt = blockIdx.x, h = blockIdx.y, t = blockIdx.z;
    const int tid  = threadIdx.x;
    const int lane = tid & 63;
    const int l31  = lane & 31;
    const int g32  = lane >> 5;
    const int th   = t*16 + h;
    const int n0   = nt*256 + (tid >> 6)*32;
    const int qoff = (t <= 1) ? 0 : NUP;             // q-side rows
    const int koff = (t == 1 || t == 2) ? NUP : 0;   // k/v-side rows
    const int mtb  = koff >> 5;

    __shared__ u16 sXh[3][32*200];
    __shared__ u16 sXT[3][192*40];

    // ---- prologue: QM B-fragments via MFMA (3-term fp16 split) ----
    f16x8 qh[12];
    {
        f16x8 bxh[12], bxl[12];
        const u16* xrh = xh_g + (size_t)(qoff + n0 + l31)*D;
        const u16* xrl = xl_g + (size_t)(qoff + n0 + l31)*D;
        #pragma unroll
        for (int ks = 0; ks < 12; ++ks) {
            bxh[ks] = *reinterpret_cast<const f16x8*>(xrh + ks*16 + g32*8);
            bxl[ks] = *reinterpret_cast<const f16x8*>(xrl + ks*16 + g32*8);
        }
        const u16* mthb = mth_g + (size_t)th*36864;
        const u16* mtlb = mtl_g + (size_t)th*36864;
        #pragma unroll
        for (int obp = 0; obp < 3; ++obp) {      // 2 obs in flight for ILP
            const int ob0 = obp*2, ob1 = obp*2 + 1;
            f32x16 a0, a1;
            #pragma unroll
            for (int i = 0; i < 16; ++i) { a0[i] = 0.0f; a1[i] = 0.0f; }
            #pragma unroll
            for (int ks = 0; ks < 12; ++ks) {
                size_t fo0 = (((size_t)ob0*12 + ks)*64 + lane)*8;
                size_t fo1 = (((size_t)ob1*12 + ks)*64 + lane)*8;
                f16x8 amh0 = *reinterpret_cast<const f16x8*>(mthb + fo0);
                f16x8 aml0 = *reinterpret_cast<const f16x8*>(mtlb + fo0);
                f16x8 amh1 = *reinterpret_cast<const f16x8*>(mthb + fo1);
                f16x8 aml1 = *reinterpret_cast<const f16x8*>(mtlb + fo1);
                a0 = __builtin_amdgcn_mfma_f32_32x32x16_f16(amh0, bxh[ks], a0, 0, 0, 0);
                a1 = __builtin_amdgcn_mfma_f32_32x32x16_f16(amh1, bxh[ks], a1, 0, 0, 0);
                a0 = __builtin_amdgcn_mfma_f32_32x32x16_f16(amh0, bxl[ks], a0, 0, 0, 0);
                a1 = __builtin_amdgcn_mfma_f32_32x32x16_f16(amh1, bxl[ks], a1, 0, 0, 0);
                a0 = __builtin_amdgcn_mfma_f32_32x32x16_f16(aml0, bxh[ks], a0, 0, 0, 0);
                a1 = __builtin_amdgcn_mfma_f32_32x32x16_f16(aml1, bxh[ks], a1, 0, 0, 0);
            }
            u32 h0[8], h1[8];
            #pragma unroll
            for (int j = 0; j < 8; ++j) {
                h0[j] = pk2h(a0[2*j], a0[2*j+1]);
                h1[j] = pk2h(a1[2*j], a1[2*j+1]);
            }
            qh[ob0*2+0] = make_bfrag(h0[0], h0[1], h0[2], h0[3], g32);
            qh[ob0*2+1] = make_bfrag(h0[4], h0[5], h0[6], h0[7], g32);
            qh[ob1*2+0] = make_bfrag(h1[0], h1[1], h1[2], h1[3], g32);
            qh[ob1*2+1] = make_bfrag(h1[4], h1[5], h1[6], h1[7], g32);
        }
    }

    f32x16 vt[6];
    #pragma unroll
    for (int ob = 0; ob < 6; ++ob)
        #pragma unroll
        for (int i = 0; i < 16; ++i) vt[ob][i] = 0.0f;

    float run_m = -3.0e38f, run_l = 0.0f;

    uint4 ld[3];
    auto load_tile = [&](int mt) {
        const int krow0 = koff + mt*32;
        #pragma unroll
        for (int i = 0; i < 3; ++i) {
            int c = tid + i*512;
            const u16* gp;
            if (c < 768) {
                int rr = c/24, cc = c - rr*24;
                gp = xh_g + (size_t)(krow0 + rr)*D + cc*8;
            } else {
                int c3 = c - 768, dd = c3 >> 2, qq = c3 & 3;
                gp = xT_g + (size_t)(mtb + mt)*6144 + dd*32 + qq*8;
            }
            ld[i] = *reinterpret_cast<const uint4*>(gp);
        }
    };
    auto store_tile = [&](int buf) {
        #pragma unroll
        for (int i = 0; i < 3; ++i) {
            int c = tid + i*512;
            u16* lp;
            if (c < 768) {
                int rr = c/24, cc = c - rr*24;  lp = &sXh[buf][rr*200 + cc*8];
            } else {
                int c3 = c - 768, dd = c3 >> 2, qq = c3 & 3;  lp = &sXT[buf][dd*40 + qq*8];
            }
            *reinterpret_cast<uint4*>(lp) = ld[i];
        }
    };
    auto SCORES = [&](int bc, f32x16 &sOut) {
        f32x16 s0, s1;
        #pragma unroll
        for (int i = 0; i < 16; ++i) { s0[i] = 0.0f; s1[i] = 0.0f; }
        __builtin_amdgcn_s_setprio(1);
        #pragma unroll
        for (int ks = 0; ks < 6; ++ks) {
            f16x8 ah0 = *reinterpret_cast<const f16x8*>(&sXh[bc][l31*200 + ks*16 + g32*8]);
            f16x8 ah1 = *reinterpret_cast<const f16x8*>(&sXh[bc][l31*200 + (ks+6)*16 + g32*8]);
            s0 = __builtin_amdgcn_mfma_f32_32x32x16_f16(ah0, qh[ks],   s0, 0, 0, 0);
            s1 = __builtin_amdgcn_mfma_f32_32x32x16_f16(ah1, qh[ks+6], s1, 0, 0, 0);
        }
        __builtin_amdgcn_s_setprio(0);
        #pragma unroll
        for (int i = 0; i < 16; ++i) sOut[i] = s0[i] + s1[i];
    };
    auto SOFTMAX = [&](f32x16 &sIn, f16x8 &pf0, f16x8 &pf1) {
        float tmax = sIn[0];
        #pragma unroll
        for (int i = 1; i < 16; ++i) tmax = fmaxf(tmax, sIn[i]);
        tmax = fmaxf(tmax, __shfl_xor(tmax, 32));
        if (__any(tmax > run_m + 8.0f)) {       // defer-rescale (T13)
            float nm = fmaxf(run_m, tmax);
            float rs = __expf(run_m - nm);
            #pragma unroll
            for (int ob = 0; ob < 6; ++ob)
                #pragma unroll
                for (int i = 0; i < 16; ++i) vt[ob][i] *= rs;
            run_l *= rs;
            run_m = nm;
        }
        float psum = 0.0f;
        u32 q[8];
        #pragma unroll
        for (int j = 0; j < 8; ++j) {
            float p0 = __expf(sIn[2*j]   - run_m);
            float p1 = __expf(sIn[2*j+1] - run_m);
            psum += p0 + p1;
            q[j] = pk2h_rtz(p0, p1);
        }
        psum += __shfl_xor(psum, 32);
        run_l += psum;
        pf0 = make_bfrag(q[0], q[1], q[2], q[3], g32);
        pf1 = make_bfrag(q[4], q[5], q[6], q[7], g32);
    };
    auto PV = [&](int bp, f16x8 pf0, f16x8 pf1) {
        __builtin_amdgcn_s_setprio(1);
        #pragma unroll
        for (int ob = 0; ob < 6; ++ob) {
            f16x8 a0 = *reinterpret_cast<const f16x8*>(&sXT[bp][(ob*32 + l31)*40 + g32*8]);
            f16x8 a1 = *reinterpret_cast<const f16x8*>(&sXT[bp][(ob*32 + l31)*40 + 16 + g32*8]);
            vt[ob] = __builtin_amdgcn_mfma_f32_32x32x16_f16(a0, pf0, vt[ob], 0, 0, 0);
            vt[ob] = __builtin_amdgcn_mfma_f32_32x32x16_f16(a1, pf1, vt[ob], 0, 0, 0);
        }
        __builtin_amdgcn_s_setprio(0);
    };

    f32x16 sA, sB;

    // ---- pipeline prologue: tile0 staged+scored; tile1 staged ----
    load_tile(0); store_tile(0); __syncthreads();
    load_tile(1);
    SCORES(0, sA);
    store_tile(1); __syncthreads();

    auto STEP = [&](int cur, f32x16 &sCur, f32x16 &sPrev, int bC, int bP, int bN) {
        if (cur < 31) load_tile(cur + 1);
        SCORES(bC, sCur);                    // MFMA(cur) issues...
        f16x8 pf0, pf1;
        SOFTMAX(sPrev, pf0, pf1);            // ...while VALU does softmax(prev)
        PV(bP, pf0, pf1);
        if (cur < 31) store_tile(bN);
        __syncthreads();
    };

    // buffers at cur=1: cur%3=1, prev=0, next=2; rotate each step
    int b0 = 1, b1 = 0, b2 = 2;
    #pragma unroll 1
    for (int m2 = 1; m2 <= 29; m2 += 2) {
        STEP(m2,     sB, sA, b0, b1, b2);
        { int tq = b1; b1 = b0; b0 = b2; b2 = tq; }
        STEP(m2 + 1, sA, sB, b0, b1, b2);
        { int tq = b1; b1 = b0; b0 = b2; b2 = tq; }
    }
    STEP(31, sB, sA, b0, b1, b2);            // scores(31), softmax+PV(30)
    // ---- epilogue: softmax + PV of tile31 (lives in buffer b0) ----
    {
        f16x8 pf0, pf1;
        SOFTMAX(sB, pf0, pf1);
        PV(b0, pf0, pf1);
    }

    // --- normalize ---
    float inv = 1.0f / run_l;
    #pragma unroll
    for (int ob = 0; ob < 6; ++ob)
        #pragma unroll
        for (int i = 0; i < 16; ++i) vt[ob][i] *= inv;

    // --- combine: Y^T[dout][n] = sum_din WT[dout][din] * Vt^T[din][n] ---
    const u16* wbase = wtp_g + (size_t)th*36864;
    f32x16 y[6];
    #pragma unroll
    for (int ob = 0; ob < 6; ++ob)
        #pragma unroll
        for (int i = 0; i < 16; ++i) y[ob][i] = 0.0f;

    #pragma unroll
    for (int ob = 0; ob < 6; ++ob) {
        u32 qq[8];
        #pragma unroll
        for (int j = 0; j < 8; ++j) qq[j] = pk2h_rtz(vt[ob][2*j], vt[ob][2*j+1]);
        #pragma unroll
        for (int half = 0; half < 2; ++half) {
            int ks = ob*2 + half;
            f16x8 bfr = half ? make_bfrag(qq[4], qq[5], qq[6], qq[7], g32)
                             : make_bfrag(qq[0], qq[1], qq[2], qq[3], g32);
            #pragma unroll
            for (int ob2 = 0; ob2 < 6; ++ob2) {
                f16x8 a = *reinterpret_cast<const f16x8*>(
                    wbase + ((((size_t)ob2*12) + ks)*64 + lane)*8);
                y[ob2] = __builtin_amdgcn_mfma_f32_32x32x16_f16(a, bfr, y[ob2], 0, 0, 0);
            }
        }
    }

    // --- write partial Y[t][h][n][dout] (fp16) ---
    u16* yrow = y_g + ((size_t)th*1024 + n0 + l31)*D;
    #pragma unroll
    for (int ob = 0; ob < 6; ++ob)
        #pragma unroll
        for (int rq = 0; rq < 4; ++rq) {
            uint2 v;
            v.x = pk2h_rtz(y[ob][rq*4+0], y[ob][rq*4+1]);
            v.y = pk2h_rtz(y[ob][rq*4+2], y[ob][rq*4+3]);
            *reinterpret_cast<uint2*>(yrow + ob*32 + rq*8 + g32*4) = v;
        }
}

// =====================================================================
// Reduce: out[p*1024+n][d] = sum_{t in pair, h} y[t][h][n][d]  (fp16 in)
// =====================================================================
__global__ __launch_bounds__(512)
void reduce_y(const u16* __restrict__ y_g, float* __restrict__ out)
{
    int gi = blockIdx.x*512 + threadIdx.x;     // < 2048*192/8
    int n = gi / 24, c = gi - n*24;
    int p = n >> 10, nn = n & 1023;
    float acc[8];
    #pragma unroll
    for (int j = 0; j < 8; ++j) acc[j] = 0.0f;
    #pragma unroll
    for (int k = 0; k < 32; ++k) {
        int tcur = p*2 + (k >> 4), hh = k & 15;
        uint4 v = *reinterpret_cast<const uint4*>(
            y_g + ((size_t)((tcur*16+hh)*1024 + nn))*D + c*8);
        u32 w[4] = {v.x, v.y, v.z, v.w};
        #pragma unroll
        for (int j = 0; j < 4; ++j) {
            acc[2*j]   += h2f((u16)(w[j] & 0xffffu));
            acc[2*j+1] += h2f((u16)(w[j] >> 16));
        }
    }
    float* op = out + (size_t)n*D + c*8;
    float4 o0 = {acc[0], acc[1], acc[2], acc[3]};
    float4 o1 = {acc[4], acc[5], acc[6], acc[7]};
    *reinterpret_cast<float4*>(op)     = o0;
    *reinterpret_cast<float4*>(op + 4) = o1;
}

// =====================================================================
// Fallback (round-1 fp32 kernel) if ws too small
// =====================================================================
__global__ __launch_bounds__(256, 2)
void attn_fused_fb(const float* __restrict__ x,
                const float* __restrict__ Muu, const float* __restrict__ Mdd,
                const float* __restrict__ Mud, const float* __restrict__ Mdu,
                const float* __restrict__ Auu, const float* __restrict__ Add,
                const float* __restrict__ Aud, const float* __restrict__ Adu,
                float* __restrict__ out)
{
    const int nt  = blockIdx.x;
    const int h   = blockIdx.y;
    const int t   = blockIdx.z;
    const int tid = threadIdx.x;
    const float* qb = (t <= 1) ? x : x + (size_t)NUP*D;
    const float* kb = (t == 0 || t == 3) ? x : x + (size_t)NUP*D;
    const float* Mp = (t==0)?Muu:(t==1)?Mud:(t==2)?Mdd:Mdu;
    const float* Ap = (t==0)?Auu:(t==1)?Aud:(t==2)?Add:Adu;
    const float* Mh = Mp + (size_t)h*32*D;
    const float* Ah = Ap + (size_t)h*32*D;
    float* ob = out + ((t>=2) ? (size_t)NUP*D : 0);

    __shared__ float sK[32*196];
    __shared__ float sQM[32*196];
    __shared__ float sS[32*33];
    __shared__ float sTmp[32*8];
    __shared__ float sR[32];
    __shared__ float sMaxRun[32];
    __shared__ float sSumRun[32];

    if (tid < 32) { sMaxRun[tid] = -3.0e38f; sSumRun[tid] = 0.0f; }
    for (int i = tid; i < 32*D/4; i += 256)
        reinterpret_cast<float4*>(sK)[i] = reinterpret_cast<const float4*>(Mh)[i];
    __syncthreads();

    #pragma unroll
    for (int kk = 0; kk < 4; ++kk) {
        int p = tid + kk*256;
        int n = p >> 5, g = p & 31;
        const float* qrow = qb + (size_t)(nt*32 + n)*D;
        float acc[6] = {0,0,0,0,0,0};
        for (int f = 0; f < 32; ++f) {
            const float* qf = qrow + f*6;
            const float* mf = sK + f*D + g*6;
            #pragma unroll
            for (int z = 0; z < 3; ++z) {
                float q0 = qf[2*z], q1 = qf[2*z+1];
                float m0 = mf[2*z], m1 = mf[2*z+1];
                acc[2*z]   += q0*m0 - q1*m1;
                acc[2*z+1] += q1*m0 + q0*m1;
            }
        }
        #pragma unroll
        for (int j = 0; j < 6; ++j) sQM[n*196 + g*6 + j] = acc[j];
    }

    const int gn = tid >> 5;
    const int cg = tid & 31;
    const int cbase = cg*6;
    float vacc[4][6];
    #pragma unroll
    for (int a = 0; a < 4; ++a)
        #pragma unroll
        for (int b = 0; b < 6; ++b) vacc[a][b] = 0.0f;

    const int txm = tid & 15, tyn = tid >> 4;

    for (int mt = 0; mt < 32; ++mt) {
        __syncthreads();
        for (int i = tid; i < 32*(D/4); i += 256) {
            int row = i / (D/4), j = i - row*(D/4);
            float4 v = reinterpret_cast<const float4*>(kb + (size_t)(mt*32 + row)*D)[j];
            *reinterpret_cast<float4*>(&sK[row*196 + j*4]) = v;
        }
        __syncthreads();

        float a00=0,a01=0,a10=0,a11=0;
        {
            const float* q0p = &sQM[tyn*196];
            const float* q1p = &sQM[(tyn+16)*196];
            const float* k0p = &sK[txm*196];
            const float* k1p = &sK[(txm+16)*196];
            for (int k = 0; k < D; k += 4) {
                float4 qa = *reinterpret_cast<const float4*>(q0p+k);
                float4 qc = *reinterpret_cast<const float4*>(q1p+k);
                float4 ka = *reinterpret_cast<const float4*>(k0p+k);
                float4 kc = *reinterpret_cast<const float4*>(k1p+k);
                a00 += qa.x*ka.x + qa.y*ka.y + qa.z*ka.z + qa.w*ka.w;
                a01 += qa.x*kc.x + qa.y*kc.y + qa.z*kc.z + qa.w*kc.w;
                a10 += qc.x*ka.x + qc.y*ka.y + qc.z*ka.z + qc.w*ka.w;
                a11 += qc.x*kc.x + qc.y*kc.y + qc.z*kc.z + qc.w*kc.w;
            }
        }
        sS[tyn*33 + txm]          = a00;
        sS[tyn*33 + txm+16]       = a01;
        sS[(tyn+16)*33 + txm]     = a10;
        sS[(tyn+16)*33 + txm+16]  = a11;
        __syncthreads();

        const int srow = tid >> 3, sj = tid & 7;
        {
            const float* r = &sS[srow*33];
            float mx = fmaxf(fmaxf(r[sj], r[sj+8]), fmaxf(r[sj+16], r[sj+24]));
            sTmp[srow*8 + sj] = mx;
        }
        __syncthreads();
        if (tid < 32) {
            float mx = sTmp[tid*8];
            #pragma unroll
            for (int j = 1; j < 8; ++j) mx = fmaxf(mx, sTmp[tid*8+j]);
            float om = sMaxRun[tid];
            float nm = fmaxf(om, mx);
            sR[tid] = __expf(om - nm);
            sMaxRun[tid] = nm;
        }
        __syncthreads();
        {
            float nm = sMaxRun[srow];
            float* r = &sS[srow*33];
            float p0 = __expf(r[sj]    - nm);
            float p1 = __expf(r[sj+8]  - nm);
            float p2 = __expf(r[sj+16] - nm);
            float p3 = __expf(r[sj+24] - nm);
            r[sj] = p0; r[sj+8] = p1; r[sj+16] = p2; r[sj+24] = p3;
            sTmp[srow*8+sj] = p0+p1+p2+p3;
        }
        __syncthreads();
        if (tid < 32) {
            float s = 0.0f;
            #pragma unroll
            for (int j = 0; j < 8; ++j) s += sTmp[tid*8+j];
            sSumRun[tid] = sSumRun[tid]*sR[tid] + s;
        }
        {
            float r0 = sR[gn*4+0], r1 = sR[gn*4+1], r2 = sR[gn*4+2], r3 = sR[gn*4+3];
            #pragma unroll
            for (int b = 0; b < 6; ++b) { vacc[0][b]*=r0; vacc[1][b]*=r1; vacc[2][b]*=r2; vacc[3][b]*=r3; }
            for (int m = 0; m < 32; ++m) {
                float p0 = sS[(gn*4+0)*33+m];
                float p1 = sS[(gn*4+1)*33+m];
                float p2 = sS[(gn*4+2)*33+m];
                float p3 = sS[(gn*4+3)*33+m];
                const float* kr = &sK[m*196 + cbase];
                #pragma unroll
                for (int b = 0; b < 6; ++b) {
                    float kv = kr[b];
                    vacc[0][b] += p0*kv;
                    vacc[1][b] += p1*kv;
                    vacc[2][b] += p2*kv;
                    vacc[3][b] += p3*kv;
                }
            }
        }
    }

    __syncthreads();
    {
        float i0 = 1.0f/sSumRun[gn*4+0], i1 = 1.0f/sSumRun[gn*4+1];
        float i2 = 1.0f/sSumRun[gn*4+2], i3 = 1.0f/sSumRun[gn*4+3];
        #pragma unroll
        for (int b = 0; b < 6; ++b) {
            sQM[(gn*4+0)*196 + cbase + b] = vacc[0][b]*i0;
            sQM[(gn*4+1)*196 + cbase + b] = vacc[1][b]*i1;
            sQM[(gn*4+2)*196 + cbase + b] = vacc[2][b]*i2;
            sQM[(gn*4+3)*196 + cbase + b] = vacc[3][b]*i3;
        }
    }
    for (int i = tid; i < 32*D/4; i += 256)
        reinterpret_cast<float4*>(sK)[i] = reinterpret_cast<const float4*>(Ah)[i];
    __syncthreads();

    #pragma unroll
    for (int kk = 0; kk < 4; ++kk) {
        int p = tid + kk*256;
        int n = p >> 5, g = p & 31;
        float acc[6] = {0,0,0,0,0,0};
        const float* vb = &sQM[n*196];
        const float* ab = &sK[g*D];
        for (int f = 0; f < 32; ++f) {
            const float* vf = vb + f*6;
            const float* af = ab + f*6;
            #pragma unroll
            for (int z = 0; z < 3; ++z) {
                float V0 = vf[2*z], V1 = vf[2*z+1];
                float A0 = af[2*z], A1 = af[2*z+1];
                acc[2*z]   += A0*V0 - A1*V1;
                acc[2*z+1] += A0*V1 + A1*V0;
            }
        }
        float* op = ob + (size_t)(nt*32 + n)*D + g*6;
        #pragma unroll
        for (int j = 0; j < 6; ++j) atomicAdd(op + j, acc[j]);
    }
}

extern "C" void kernel_launch(void* const* d_in, const int* in_sizes, int n_in,
                              void* d_out, int out_size, void* d_ws, size_t ws_size,
                              hipStream_t stream) {
    const float* x   = (const float*)d_in[0];
    const float* Muu = (const float*)d_in[1];
    const float* Mdd = (const float*)d_in[2];
    const float* Mud = (const float*)d_in[3];
    const float* Mdu = (const float*)d_in[4];
    const float* Auu = (const float*)d_in[5];
    const float* Add = (const float*)d_in[6];
    const float* Aud = (const float*)d_in[7];
    const float* Adu = (const float*)d_in[8];
    float* outp = (float*)d_out;

    if (ws_size >= WS_NEED) {
        char* ws = (char*)d_ws;
        u16* xh  = (u16*)(ws + XH_OFF);
        u16* xl  = (u16*)(ws + XL_OFF);
        u16* xT  = (u16*)(ws + XT_OFF);
        u16* wtp = (u16*)(ws + WTP_OFF);
        u16* mth = (u16*)(ws + MTH_OFF);
        u16* mtl = (u16*)(ws + MTL_OFF);
        u16* y   = (u16*)(ws + Y_OFF);

        prep_all<<<5376, 512, 0, stream>>>(x, Muu, Mdd, Mud, Mdu,
                                           Auu, Add, Aud, Adu,
                                           xh, xl, xT, wtp, mth, mtl);
        attn_mfma<<<dim3(4, 16, 4), 512, 0, stream>>>(xh, xl, xT, wtp, mth, mtl, y);
        reduce_y<<<96, 512, 0, stream>>>(y, outp);
    } else {
        (void)hipMemsetAsync(d_out, 0, (size_t)out_size * sizeof(float), stream);
        attn_fused_fb<<<dim3(32, 16, 4), 256, 0, stream>>>(x, Muu, Mdd, Mud, Mdu,
                                                           Auu, Add, Aud, Adu, outp);
    }
}